// Round 12
// baseline (2667.908 us; speedup 1.0000x reference)
//
#include <hip/hip_runtime.h>
#include <hip/hip_bf16.h>
#include <cstdint>
#include <cstddef>

#define NB 4
#define NT 1024
#define NE 768
#define NH 12
#define NHS 64
#define NL 6
#define NFF 3072
#define NV 50257
#define NVP 50304          // 50257 padded to /128
#define NTOK (NB*NT)       // 4096
#define NCB_LM (NVP/128)   // 393 col-blocks in LM head
#define QKVS 2304          // fused QKV row stride

typedef __attribute__((ext_vector_type(8))) short short8;
typedef __attribute__((ext_vector_type(4))) float f32x4;
typedef __hip_bfloat16 bf16;

// ---------------- embedding ----------------
__global__ __launch_bounds__(256) void embed_kernel(
    const int* __restrict__ idx, const float* __restrict__ tok,
    const float* __restrict__ pos, float* __restrict__ x)
{
  int bt = blockIdx.x;
  int token = idx[bt];
  int t = bt & (NT - 1);
  const float* tr = tok + (size_t)token * NE;
  const float* pr = pos + (size_t)t * NE;
  float* xr = x + (size_t)bt * NE;
  for (int i = threadIdx.x; i < NE; i += 256)
    xr[i] = tr[i] + pr[i];
}

// ---------------- layernorm (row = 768), bf16 out ----------------
__global__ __launch_bounds__(256) void ln_kernel(
    const float* __restrict__ in, const float* __restrict__ sc,
    const float* __restrict__ bi, bf16* __restrict__ out)
{
  int row = blockIdx.x, tid = threadIdx.x;
  const float* xr = in + (size_t)row * NE;
  float v0 = xr[tid], v1 = xr[tid + 256], v2 = xr[tid + 512];
  float s = v0 + v1 + v2;
  float ss = v0 * v0 + v1 * v1 + v2 * v2;
  #pragma unroll
  for (int o = 32; o > 0; o >>= 1) {
    s  += __shfl_xor(s, o);
    ss += __shfl_xor(ss, o);
  }
  __shared__ float r1[4], r2[4];
  if ((tid & 63) == 0) { r1[tid >> 6] = s; r2[tid >> 6] = ss; }
  __syncthreads();
  float tot = r1[0] + r1[1] + r1[2] + r1[3];
  float tss = r2[0] + r2[1] + r2[2] + r2[3];
  float mu  = tot * (1.f / NE);
  float var = tss * (1.f / NE) - mu * mu;
  float rs  = rsqrtf(var + 1e-5f);
  bf16* orow = out + (size_t)row * NE;
  orow[tid]       = __float2bfloat16((v0 - mu) * rs * sc[tid]       + bi[tid]);
  orow[tid + 256] = __float2bfloat16((v1 - mu) * rs * sc[tid + 256] + bi[tid + 256]);
  orow[tid + 512] = __float2bfloat16((v2 - mu) * rs * sc[tid + 512] + bi[tid + 512]);
}

// ------- transpose+convert: src f32 [R][Cs] -> dst bf16 [Cd][R], batched over z -------
__global__ __launch_bounds__(256) void tconv_kernel(
    const float* __restrict__ src, bf16* __restrict__ dst,
    int R, int Cs, int Cd, int zdiv,
    size_t srcZstr, size_t dstLstr, size_t dstHstr)
{
  __shared__ float t[32][33];
  int z = blockIdx.z;
  int l = z / zdiv, h = z - l * zdiv;
  src += (size_t)z * srcZstr;
  dst += (size_t)l * dstLstr + (size_t)h * dstHstr;
  int c0 = blockIdx.x * 32, r0 = blockIdx.y * 32;
  int tx = threadIdx.x & 31, ty = threadIdx.x >> 5;
  #pragma unroll
  for (int i = 0; i < 32; i += 8) {
    int r = r0 + ty + i, c = c0 + tx;
    t[ty + i][tx] = (c < Cs) ? src[(size_t)r * Cs + c] : 0.f;
  }
  __syncthreads();
  #pragma unroll
  for (int i = 0; i < 32; i += 8) {
    int c = c0 + ty + i, r = r0 + tx;
    if (c < Cd) dst[(size_t)c * R + r] = __float2bfloat16(t[tx][ty + i]);
  }
}

// ---------------- bf16 MFMA GEMM (m97 structure) — layer GEMMs (R9 proven) ----------------
template<int MREP, bool SWZ>
__global__ __launch_bounds__(256) void gemm_bf(
    const bf16* __restrict__ A,
    const bf16* __restrict__ BT,
    float* __restrict__ Cf, bf16* __restrict__ Cbf,
    const float* __restrict__ bias, const float* __restrict__ Rres,
    float* __restrict__ ps,
    int M, int N, int K, int relu, int ncb)
{
  constexpr int BMT = MREP * 32;
  __shared__ bf16 As[BMT][64];
  __shared__ bf16 Bs[128][64];
  __shared__ float ps2[BMT][2];
  int tid = threadIdx.x;
  int lane = tid & 63;
  int w = __builtin_amdgcn_readfirstlane(tid >> 6);
  int wr = w >> 1, wc = w & 1;
  int cb = blockIdx.x;
  int row0 = blockIdx.y * BMT;
  int col0 = cb * 128;

  f32x4 acc[MREP][4] = {};

  for (int k0 = 0; k0 < K; k0 += 64) {
    #pragma unroll
    for (int r = 0; r < MREP; ++r) {
      int c = r * 256 + tid;
      int trow = c >> 3;
      int schunk = SWZ ? ((c & 7) ^ (trow & 7)) : (c & 7);
      const bf16* ga = A + (size_t)(row0 + trow) * K + k0 + (schunk << 3);
      __builtin_amdgcn_global_load_lds(
          (const __attribute__((address_space(1))) void*)ga,
          (__attribute__((address_space(3))) void*)((char*)&As[0][0] + (unsigned)c * 16),
          16, 0, 0);
    }
    #pragma unroll
    for (int r = 0; r < 4; ++r) {
      int c = r * 256 + tid;
      int trow = c >> 3;
      int schunk = SWZ ? ((c & 7) ^ (trow & 7)) : (c & 7);
      const bf16* gb = BT + (size_t)(col0 + trow) * K + k0 + (schunk << 3);
      __builtin_amdgcn_global_load_lds(
          (const __attribute__((address_space(1))) void*)gb,
          (__attribute__((address_space(3))) void*)((char*)&Bs[0][0] + (unsigned)c * 16),
          16, 0, 0);
    }
    __syncthreads();
    int l15 = lane & 15;
    int g8 = (lane >> 4) << 3;
    int sx = SWZ ? ((l15 & 7) << 3) : 0;
    #pragma unroll
    for (int kk = 0; kk < 64; kk += 32) {
      short8 a[MREP], b[4];
      #pragma unroll
      for (int m = 0; m < MREP; ++m)
        a[m] = *(const short8*)&As[wr * (MREP * 16) + m * 16 + l15][(kk + g8) ^ sx];
      #pragma unroll
      for (int n = 0; n < 4; ++n)
        b[n] = *(const short8*)&Bs[wc * 64 + n * 16 + l15][(kk + g8) ^ sx];
      #pragma unroll
      for (int m = 0; m < MREP; ++m)
        #pragma unroll
        for (int n = 0; n < 4; ++n)
          acc[m][n] = __builtin_amdgcn_mfma_f32_16x16x32_bf16(a[m], b[n], acc[m][n], 0, 0, 0);
    }
    __syncthreads();
  }

  int cr = lane >> 4;
  int cc = lane & 15;
  #pragma unroll
  for (int m = 0; m < MREP; ++m) {
    #pragma unroll
    for (int n = 0; n < 4; ++n) {
      int col = col0 + wc * 64 + n * 16 + cc;
      if (col >= N) continue;
      float bv = bias ? bias[col] : 0.f;
      #pragma unroll
      for (int e = 0; e < 4; ++e) {
        int row = row0 + wr * (MREP * 16) + m * 16 + cr * 4 + e;
        float v = acc[m][n][e] + bv;
        size_t off = (size_t)row * N + col;
        if (Rres) v += Rres[off];
        if (relu) v = fmaxf(v, 0.f);
        if (Cf)  Cf[off] = v;
        if (Cbf) Cbf[off] = __float2bfloat16(v);
      }
    }
  }

  if (ps) {
    #pragma unroll
    for (int m = 0; m < MREP; ++m) {
      #pragma unroll
      for (int e = 0; e < 4; ++e) {
        float ssum = 0.f;
        #pragma unroll
        for (int n = 0; n < 4; ++n) {
          int col = col0 + wc * 64 + n * 16 + cc;
          float val = (col < N) ? (acc[m][n][e] + (bias ? bias[col] : 0.f)) : -1e30f;
          ssum += __expf(val);
        }
        ssum += __shfl_xor(ssum, 1);
        ssum += __shfl_xor(ssum, 2);
        ssum += __shfl_xor(ssum, 4);
        ssum += __shfl_xor(ssum, 8);
        if (cc == 0) {
          int rl = wr * (MREP * 16) + m * 16 + cr * 4 + e;
          ps2[rl][wc] = ssum;
        }
      }
    }
    __syncthreads();
    for (int i = tid; i < MREP * 32; i += 256) {
      size_t o = (size_t)(row0 + i) * ncb + cb;
      ps[o] = ps2[i][0] + ps2[i][1];
    }
  }
}

// ---------------- LM-head GEMM: panel-persistent + 2-phase pipeline ----------------
// grid (393 panels, 4 row-groups); each block owns one 128-col B panel and sweeps
// NBAND=8 row-bands of A. B re-staged per band hits L2/L3 (all panels = 77MB fit
// L3) -> HBM reads drop to compulsory ~90MB. Inner schedule = R10's proven 2-phase:
// STAGE(next tile) -> MFMA(cur) -> [band epilogue] -> vmcnt(0) -> barrier. The
// per-band epilogue (C stores + exp partials) sits BEFORE the drain, covering the
// next band's stage latency.
#define LBK 32
#define LMK 768
#define NKSTEP (LMK / LBK)   // 24
#define NBAND 8
__global__ __launch_bounds__(256) void lm_gemm(
    const bf16* __restrict__ A, const bf16* __restrict__ BT,
    float* __restrict__ Cf, const float* __restrict__ bias,
    float* __restrict__ ps, int M, int N, int ncb)
{
  __shared__ bf16 As[2][128][LBK];
  __shared__ bf16 Bs[2][128][LBK];
  __shared__ float ps2[128][2];
  int tid = threadIdx.x;
  int lane = tid & 63;
  int w = __builtin_amdgcn_readfirstlane(tid >> 6);
  int wr = w >> 1, wc = w & 1;
  int col0 = blockIdx.x * 128;
  int band0 = blockIdx.y * NBAND;
  int l15 = lane & 15;
  int g8 = (lane >> 4) << 3;
  int cr = lane >> 4;
  int cc = lane & 15;

  f32x4 acc[4][4] = {};

#define LM_STAGE(b, band, t)                                                   \
  {                                                                            \
    int row0s = (band0 + (band)) * 128;                                        \
    int k0 = (t) * LBK;                                                        \
    _Pragma("unroll")                                                          \
    for (int r = 0; r < 2; ++r) {                                              \
      int c = r * 256 + tid;                                                   \
      int trow = c >> 2, tcol = (c & 3) << 3;                                  \
      const bf16* ga = A + (size_t)(row0s + trow) * LMK + k0 + tcol;           \
      __builtin_amdgcn_global_load_lds(                                        \
          (const __attribute__((address_space(1))) void*)ga,                   \
          (__attribute__((address_space(3))) void*)((char*)&As[b][0][0] + (unsigned)c * 16), \
          16, 0, 0);                                                           \
    }                                                                          \
    _Pragma("unroll")                                                          \
    for (int r = 0; r < 2; ++r) {                                              \
      int c = r * 256 + tid;                                                   \
      int trow = c >> 2, tcol = (c & 3) << 3;                                  \
      const bf16* gb = BT + (size_t)(col0 + trow) * LMK + k0 + tcol;           \
      __builtin_amdgcn_global_load_lds(                                        \
          (const __attribute__((address_space(1))) void*)gb,                   \
          (__attribute__((address_space(3))) void*)((char*)&Bs[b][0][0] + (unsigned)c * 16), \
          16, 0, 0);                                                           \
    }                                                                          \
  }

  // prologue: stage (band 0, t 0)
  LM_STAGE(0, 0, 0);
  asm volatile("s_waitcnt vmcnt(0)" ::: "memory");
  __builtin_amdgcn_s_barrier();

  int cur = 0;
  int sband = 0, st = 1;          // next tile to stage
  for (int band = 0; band < NBAND; ++band) {
    for (int t = 0; t < NKSTEP; ++t) {
      bool last = (band == NBAND - 1) && (t == NKSTEP - 1);
      if (!last) {
        LM_STAGE(cur ^ 1, sband, st);
        if (++st == NKSTEP) { st = 0; ++sband; }
      }
      // compute tile (band, t) from buffer cur
      short8 a[4], bb[4];
      #pragma unroll
      for (int m = 0; m < 4; ++m)
        a[m] = *(const short8*)&As[cur][wr * 64 + m * 16 + l15][g8];
      #pragma unroll
      for (int n = 0; n < 4; ++n)
        bb[n] = *(const short8*)&Bs[cur][wc * 64 + n * 16 + l15][g8];
      #pragma unroll
      for (int m = 0; m < 4; ++m)
        #pragma unroll
        for (int n = 0; n < 4; ++n)
          acc[m][n] = __builtin_amdgcn_mfma_f32_16x16x32_bf16(a[m], bb[n], acc[m][n], 0, 0, 0);

      if (t == NKSTEP - 1) {
        // band epilogue: C stores + fused sum-exp partials; covers next stage's latency
        int row0 = (band0 + band) * 128;
        #pragma unroll
        for (int m = 0; m < 4; ++m) {
          #pragma unroll
          for (int n = 0; n < 4; ++n) {
            int col = col0 + wc * 64 + n * 16 + cc;
            if (col >= N) continue;
            float bv = bias[col];
            #pragma unroll
            for (int e = 0; e < 4; ++e) {
              int row = row0 + wr * 64 + m * 16 + cr * 4 + e;
              Cf[(size_t)row * N + col] = acc[m][n][e] + bv;
            }
          }
        }
        #pragma unroll
        for (int m = 0; m < 4; ++m) {
          #pragma unroll
          for (int e = 0; e < 4; ++e) {
            float ssum = 0.f;
            #pragma unroll
            for (int n = 0; n < 4; ++n) {
              int col = col0 + wc * 64 + n * 16 + cc;
              float val = (col < N) ? (acc[m][n][e] + bias[col]) : -1e30f;
              ssum += __expf(val);
            }
            ssum += __shfl_xor(ssum, 1);
            ssum += __shfl_xor(ssum, 2);
            ssum += __shfl_xor(ssum, 4);
            ssum += __shfl_xor(ssum, 8);
            if (cc == 0) ps2[wr * 64 + m * 16 + cr * 4 + e][wc] = ssum;
          }
        }
        __syncthreads();
        for (int i = tid; i < 128; i += 256) {
          size_t o = (size_t)(row0 + i) * ncb + blockIdx.x;
          ps[o] = ps2[i][0] + ps2[i][1];
        }
        #pragma unroll
        for (int m = 0; m < 4; ++m)
          #pragma unroll
          for (int n = 0; n < 4; ++n)
            acc[m][n] = f32x4{0.f, 0.f, 0.f, 0.f};
      }

      asm volatile("s_waitcnt vmcnt(0)" ::: "memory");
      __builtin_amdgcn_s_barrier();
      cur ^= 1;
    }
  }
#undef LM_STAGE
}

// ---------------- flash attention, MFMA, online softmax ----------------
static __device__ inline unsigned short bfbits(float x) {
  bf16 h = __float2bfloat16(x);
  return *reinterpret_cast<unsigned short*>(&h);
}

__global__ __launch_bounds__(256) void fattn_kernel(
    const bf16* __restrict__ QKV, bf16* __restrict__ O)
{
  __shared__ unsigned short Ks[64][72];
  __shared__ unsigned short Vt[64][72];
  __shared__ unsigned short Pl[4][16][72];
  int qt = blockIdx.x, h = blockIdx.y, b = blockIdx.z;
  int tid = threadIdx.x;
  int lane = tid & 63;
  int w = tid >> 6;
  int l15 = lane & 15, g = lane >> 4;
  int brow = b * NT;
  int qbase = qt * 64;
  int q_loc = w * 16 + l15;

  short8 bq[2];
  {
    const bf16* qp = QKV + (size_t)(brow + qbase + q_loc) * QKVS + h * 64 + g * 8;
    bq[0] = *(const short8*)qp;
    bq[1] = *(const short8*)(qp + 32);
  }

  float m_run = -1e30f, l_run = 0.f;
  f32x4 acc[4] = {};

  for (int kt = 0; kt <= qt; ++kt) {
    int s0 = kt * 64;
    #pragma unroll
    for (int i = 0; i < 2; ++i) {
      int c = tid + i * 256;
      int row = c >> 3, colg = (c & 7) * 8;
      const bf16* kp = QKV + (size_t)(brow + s0 + row) * QKVS + NE + h * 64 + colg;
      const bf16* vp = QKV + (size_t)(brow + s0 + row) * QKVS + 2 * NE + h * 64 + colg;
      short8 kv = *(const short8*)kp;
      short8 vv = *(const short8*)vp;
      *(short8*)&Ks[row][colg] = kv;
      #pragma unroll
      for (int j = 0; j < 8; ++j)
        Vt[colg + j][row] = (unsigned short)vv[j];
    }
    __syncthreads();

    f32x4 sf[4] = {};
    #pragma unroll
    for (int kk = 0; kk < 2; ++kk) {
      #pragma unroll
      for (int m = 0; m < 4; ++m) {
        short8 a = *(const short8*)&Ks[m * 16 + l15][kk * 32 + g * 8];
        sf[m] = __builtin_amdgcn_mfma_f32_16x16x32_bf16(a, bq[kk], sf[m], 0, 0, 0);
      }
    }

    float sv[4][4];
    float mx = -1e30f;
    bool diag = (kt == qt);
    #pragma unroll
    for (int m = 0; m < 4; ++m)
      #pragma unroll
      for (int e = 0; e < 4; ++e) {
        float v = sf[m][e] * 0.125f;
        if (diag) {
          int sl = m * 16 + g * 4 + e;
          if (sl > q_loc) v = -1e30f;
        }
        sv[m][e] = v;
        mx = fmaxf(mx, v);
      }
    mx = fmaxf(mx, __shfl_xor(mx, 16));
    mx = fmaxf(mx, __shfl_xor(mx, 32));
    float m_new = fmaxf(m_run, mx);
    float p[4][4];
    float rs = 0.f;
    #pragma unroll
    for (int m = 0; m < 4; ++m)
      #pragma unroll
      for (int e = 0; e < 4; ++e) {
        float pe = __expf(sv[m][e] - m_new);
        p[m][e] = pe;
        rs += pe;
      }
    rs += __shfl_xor(rs, 16);
    rs += __shfl_xor(rs, 32);
    float sc_old = __expf(m_run - m_new);
    l_run = l_run * sc_old + rs;
    m_run = m_new;
    #pragma unroll
    for (int dm = 0; dm < 4; ++dm)
      #pragma unroll
      for (int e = 0; e < 4; ++e)
        acc[dm][e] *= sc_old;

    #pragma unroll
    for (int m = 0; m < 4; ++m)
      #pragma unroll
      for (int ep = 0; ep < 2; ++ep) {
        unsigned u = (unsigned)bfbits(p[m][2 * ep]) |
                     ((unsigned)bfbits(p[m][2 * ep + 1]) << 16);
        *(unsigned*)&Pl[w][l15][m * 16 + g * 4 + ep * 2] = u;
      }

    #pragma unroll
    for (int ks = 0; ks < 2; ++ks) {
      short8 pb = *(const short8*)&Pl[w][l15][ks * 32 + g * 8];
      #pragma unroll
      for (int dm = 0; dm < 4; ++dm) {
        short8 av = *(const short8*)&Vt[dm * 16 + l15][ks * 32 + g * 8];
        acc[dm] = __builtin_amdgcn_mfma_f32_16x16x32_bf16(av, pb, acc[dm], 0, 0, 0);
      }
    }
    __syncthreads();
  }

  float inv = 1.f / l_run;
  bf16* op = O + (size_t)(brow + qbase + q_loc) * NE + h * 64;
  #pragma unroll
  for (int dm = 0; dm < 4; ++dm)
    #pragma unroll
    for (int ep = 0; ep < 2; ++ep) {
      int d = dm * 16 + g * 4 + ep * 2;
      unsigned u = (unsigned)bfbits(acc[dm][2 * ep] * inv) |
                   ((unsigned)bfbits(acc[dm][2 * ep + 1] * inv) << 16);
      *(unsigned*)((unsigned short*)op + d) = u;
    }
}

// ---------------- NLL from fused sum-exp partials (M=0 shift) ----------------
__global__ __launch_bounds__(128) void nll_finish(
    const float* __restrict__ ps,
    const float* __restrict__ logits, const int* __restrict__ targets,
    float* __restrict__ nll)
{
  int row = blockIdx.x, tid = threadIdx.x;
  float s = 0.f;
  for (int i = tid; i < NCB_LM; i += 128)
    s += ps[(size_t)row * NCB_LM + i];
  #pragma unroll
  for (int o = 32; o > 0; o >>= 1) s += __shfl_xor(s, o);
  __shared__ float ss[2];
  if ((tid & 63) == 0) ss[tid >> 6] = s;
  __syncthreads();
  if (tid == 0) {
    float S = ss[0] + ss[1];
    float tgt = logits[(size_t)row * NV + targets[row]];
    nll[row] = logf(S) - tgt;
  }
}

__global__ __launch_bounds__(256) void loss_kernel(
    const float* __restrict__ nll, float* __restrict__ out)
{
  int tid = threadIdx.x;
  float s = 0.f;
  for (int i = tid; i < NTOK; i += 256) s += nll[i];
  #pragma unroll
  for (int o = 32; o > 0; o >>= 1) s += __shfl_xor(s, o);
  __shared__ float red[4];
  if ((tid & 63) == 0) red[tid >> 6] = s;
  __syncthreads();
  if (tid == 0) out[0] = (red[0] + red[1] + red[2] + red[3]) * (1.f / NTOK);
}

// ---------------- host ----------------
static inline void gemm(const bf16* A, const bf16* BT,
                        float* Cf, bf16* Cbf,
                        const float* bias, const float* Rres, float* ps,
                        int M, int N, int Npad, int K, int relu,
                        int mrep, hipStream_t st)
{
  int ncb = Npad / 128;
  dim3 g(ncb, M / (mrep * 32));
  if (mrep == 4)
    gemm_bf<4, true><<<g, dim3(256), 0, st>>>(A, BT, Cf, Cbf, bias, Rres, ps, M, N, K, relu, ncb);
  else
    gemm_bf<2, true><<<g, dim3(256), 0, st>>>(A, BT, Cf, Cbf, bias, Rres, ps, M, N, K, relu, ncb);
}

extern "C" void kernel_launch(void* const* d_in, const int* in_sizes, int n_in,
                              void* d_out, int out_size, void* d_ws, size_t ws_size,
                              hipStream_t stream)
{
  const int*   idx     = (const int*)  d_in[0];
  const int*   targets = (const int*)  d_in[1];
  const float* tok_emb = (const float*)d_in[2];
  const float* pos_emb = (const float*)d_in[3];
  const float* Wq      = (const float*)d_in[4];
  const float* Wk      = (const float*)d_in[5];
  const float* Wv      = (const float*)d_in[6];
  const float* Wo      = (const float*)d_in[7];
  const float* bo      = (const float*)d_in[8];
  const float* ln1_s   = (const float*)d_in[9];
  const float* ln1_b   = (const float*)d_in[10];
  const float* ln2_s   = (const float*)d_in[11];
  const float* ln2_b   = (const float*)d_in[12];
  const float* W1      = (const float*)d_in[13];
  const float* b1      = (const float*)d_in[14];
  const float* W2      = (const float*)d_in[15];
  const float* b2      = (const float*)d_in[16];
  const float* lnf_s   = (const float*)d_in[17];
  const float* lnf_b   = (const float*)d_in[18];
  const float* Wlm     = (const float*)d_in[19];
  const float* blm     = (const float*)d_in[20];
  float* out = (float*)d_out;

  const size_t XE = (size_t)NTOK * NE;
  char* p = (char*)d_ws;
  float* x     = (float*)p;         p += XE * 4;
  bf16* h_bf   = (bf16*)p;          p += XE * 2;
  bf16* qkv_bf = (bf16*)p;          p += (size_t)NTOK * QKVS * 2;
  bf16* att_bf = (bf16*)p;          p += XE * 2;
  bf16* f_bf   = (bf16*)p;          p += (size_t)NTOK * NFF * 2;
  bf16* wqkv_a = (bf16*)p;          p += (size_t)NL * QKVS * NE * 2;
  bf16* wto_a  = (bf16*)p;          p += (size_t)NL * NE * NE * 2;
  bf16* wt1_a  = (bf16*)p;          p += (size_t)NL * NFF * NE * 2;
  bf16* wt2_a  = (bf16*)p;          p += (size_t)NL * NE * NFF * 2;
  bf16* wtlm   = (bf16*)p;          p += (size_t)NVP * NE * 2;
  float* psb   = (float*)p;         p += (size_t)NTOK * NCB_LM * 4;
  float* nll   = (float*)p;         p += (size_t)NTOK * 4;

  embed_kernel<<<dim3(NTOK), dim3(256), 0, stream>>>(idx, tok_emb, pos_emb, x);

  // ---- all weight transposes upfront, batched over layers (7 launches) ----
  tconv_kernel<<<dim3(2, 24, NL * NH), dim3(256), 0, stream>>>(
      Wq, wqkv_a, NE, NHS, NHS, NH,
      (size_t)NE * NHS, (size_t)QKVS * NE, (size_t)NHS * NE);
  tconv_kernel<<<dim3(2, 24, NL * NH), dim3(256), 0, stream>>>(
      Wk, wqkv_a + (size_t)NE * NE, NE, NHS, NHS, NH,
      (size_t)NE * NHS, (size_t)QKVS * NE, (size_t)NHS * NE);
  tconv_kernel<<<dim3(2, 24, NL * NH), dim3(256), 0, stream>>>(
      Wv, wqkv_a + (size_t)2 * NE * NE, NE, NHS, NHS, NH,
      (size_t)NE * NHS, (size_t)QKVS * NE, (size_t)NHS * NE);
  tconv_kernel<<<dim3(24, 24, NL), dim3(256), 0, stream>>>(
      Wo, wto_a, NE, NE, NE, 1, (size_t)NE * NE, (size_t)NE * NE, 0);
  tconv_kernel<<<dim3(96, 24, NL), dim3(256), 0, stream>>>(
      W1, wt1_a, NE, NFF, NFF, 1, (size_t)NE * NFF, (size_t)NFF * NE, 0);
  tconv_kernel<<<dim3(24, 96, NL), dim3(256), 0, stream>>>(
      W2, wt2_a, NFF, NE, NE, 1, (size_t)NFF * NE, (size_t)NE * NFF, 0);
  tconv_kernel<<<dim3(NVP / 32, 24, 1), dim3(256), 0, stream>>>(
      Wlm, wtlm, NE, NV, NVP, 1, 0, 0, 0);

  for (int l = 0; l < NL; ++l) {
    ln_kernel<<<dim3(NTOK), dim3(256), 0, stream>>>(x, ln1_s + l*NE, ln1_b + l*NE, h_bf);

    gemm(h_bf, wqkv_a + (size_t)l * QKVS * NE, nullptr, qkv_bf, nullptr, nullptr, nullptr,
         NTOK, QKVS, QKVS, NE, 0, 4, stream);

    fattn_kernel<<<dim3(NT / 64, NH, NB), dim3(256), 0, stream>>>(qkv_bf, att_bf);

    gemm(att_bf, wto_a + (size_t)l * NE * NE, x, nullptr, bo + l*NE, x, nullptr,
         NTOK, NE, NE, NE, 0, 2, stream);

    ln_kernel<<<dim3(NTOK), dim3(256), 0, stream>>>(x, ln2_s + l*NE, ln2_b + l*NE, h_bf);

    gemm(h_bf, wt1_a + (size_t)l * NFF * NE, nullptr, f_bf, b1 + l*NFF, nullptr, nullptr,
         NTOK, NFF, NFF, NE, 1, 4, stream);
    gemm(f_bf, wt2_a + (size_t)l * NE * NFF, x, nullptr, b2 + l*NE, x, nullptr,
         NTOK, NE, NE, NFF, 0, 2, stream);
  }

  ln_kernel<<<dim3(NTOK), dim3(256), 0, stream>>>(x, lnf_s, lnf_b, h_bf);

  // LM head: panel-persistent 2-phase pipeline; grid (panels, row-groups of 8 bands).
  {
    dim3 g(NCB_LM, NTOK / (NBAND * 128));   // (393, 4)
    lm_gemm<<<g, dim3(256), 0, stream>>>(h_bf, wtlm, out, blm, psb,
                                         NTOK, NV, NCB_LM);
  }

  nll_finish<<<dim3(NTOK), dim3(128), 0, stream>>>(psb, out, targets, nll);
  loss_kernel<<<dim3(1), dim3(256), 0, stream>>>(nll, out + (size_t)NTOK * NV);
}

// Round 13
// 2114.958 us; speedup vs baseline: 1.2614x; 1.2614x over previous
//
#include <hip/hip_runtime.h>
#include <hip/hip_bf16.h>
#include <cstdint>
#include <cstddef>

#define NB 4
#define NT 1024
#define NE 768
#define NH 12
#define NHS 64
#define NL 6
#define NFF 3072
#define NV 50257
#define NVP 50304          // 50257 padded to /128
#define NTOK (NB*NT)       // 4096
#define NCB_LM (NVP/128)   // 393 col-blocks in LM head
#define QKVS 2304          // fused QKV row stride

typedef __attribute__((ext_vector_type(8))) short short8;
typedef __attribute__((ext_vector_type(4))) float f32x4;
typedef __hip_bfloat16 bf16;

// ---------------- embedding ----------------
__global__ __launch_bounds__(256) void embed_kernel(
    const int* __restrict__ idx, const float* __restrict__ tok,
    const float* __restrict__ pos, float* __restrict__ x)
{
  int bt = blockIdx.x;
  int token = idx[bt];
  int t = bt & (NT - 1);
  const float* tr = tok + (size_t)token * NE;
  const float* pr = pos + (size_t)t * NE;
  float* xr = x + (size_t)bt * NE;
  for (int i = threadIdx.x; i < NE; i += 256)
    xr[i] = tr[i] + pr[i];
}

// ---------------- layernorm (row = 768), bf16 out ----------------
__global__ __launch_bounds__(256) void ln_kernel(
    const float* __restrict__ in, const float* __restrict__ sc,
    const float* __restrict__ bi, bf16* __restrict__ out)
{
  int row = blockIdx.x, tid = threadIdx.x;
  const float* xr = in + (size_t)row * NE;
  float v0 = xr[tid], v1 = xr[tid + 256], v2 = xr[tid + 512];
  float s = v0 + v1 + v2;
  float ss = v0 * v0 + v1 * v1 + v2 * v2;
  #pragma unroll
  for (int o = 32; o > 0; o >>= 1) {
    s  += __shfl_xor(s, o);
    ss += __shfl_xor(ss, o);
  }
  __shared__ float r1[4], r2[4];
  if ((tid & 63) == 0) { r1[tid >> 6] = s; r2[tid >> 6] = ss; }
  __syncthreads();
  float tot = r1[0] + r1[1] + r1[2] + r1[3];
  float tss = r2[0] + r2[1] + r2[2] + r2[3];
  float mu  = tot * (1.f / NE);
  float var = tss * (1.f / NE) - mu * mu;
  float rs  = rsqrtf(var + 1e-5f);
  bf16* orow = out + (size_t)row * NE;
  orow[tid]       = __float2bfloat16((v0 - mu) * rs * sc[tid]       + bi[tid]);
  orow[tid + 256] = __float2bfloat16((v1 - mu) * rs * sc[tid + 256] + bi[tid + 256]);
  orow[tid + 512] = __float2bfloat16((v2 - mu) * rs * sc[tid + 512] + bi[tid + 512]);
}

// ------- transpose+convert: src f32 [R][Cs] -> dst bf16 [Cd][R], batched over z -------
__global__ __launch_bounds__(256) void tconv_kernel(
    const float* __restrict__ src, bf16* __restrict__ dst,
    int R, int Cs, int Cd, int zdiv,
    size_t srcZstr, size_t dstLstr, size_t dstHstr)
{
  __shared__ float t[32][33];
  int z = blockIdx.z;
  int l = z / zdiv, h = z - l * zdiv;
  src += (size_t)z * srcZstr;
  dst += (size_t)l * dstLstr + (size_t)h * dstHstr;
  int c0 = blockIdx.x * 32, r0 = blockIdx.y * 32;
  int tx = threadIdx.x & 31, ty = threadIdx.x >> 5;
  #pragma unroll
  for (int i = 0; i < 32; i += 8) {
    int r = r0 + ty + i, c = c0 + tx;
    t[ty + i][tx] = (c < Cs) ? src[(size_t)r * Cs + c] : 0.f;
  }
  __syncthreads();
  #pragma unroll
  for (int i = 0; i < 32; i += 8) {
    int c = c0 + ty + i, r = r0 + tx;
    if (c < Cd) dst[(size_t)c * R + r] = __float2bfloat16(t[tx][ty + i]);
  }
}

// ---------------- bf16 MFMA GEMM (m97 structure) — layer GEMMs (R9 proven) ----------------
template<int MREP, bool SWZ>
__global__ __launch_bounds__(256) void gemm_bf(
    const bf16* __restrict__ A,
    const bf16* __restrict__ BT,
    float* __restrict__ Cf, bf16* __restrict__ Cbf,
    const float* __restrict__ bias, const float* __restrict__ Rres,
    float* __restrict__ ps,
    int M, int N, int K, int relu, int ncb)
{
  constexpr int BMT = MREP * 32;
  __shared__ bf16 As[BMT][64];
  __shared__ bf16 Bs[128][64];
  __shared__ float ps2[BMT][2];
  int tid = threadIdx.x;
  int lane = tid & 63;
  int w = __builtin_amdgcn_readfirstlane(tid >> 6);
  int wr = w >> 1, wc = w & 1;
  int cb = blockIdx.x;
  int row0 = blockIdx.y * BMT;
  int col0 = cb * 128;

  f32x4 acc[MREP][4] = {};

  for (int k0 = 0; k0 < K; k0 += 64) {
    #pragma unroll
    for (int r = 0; r < MREP; ++r) {
      int c = r * 256 + tid;
      int trow = c >> 3;
      int schunk = SWZ ? ((c & 7) ^ (trow & 7)) : (c & 7);
      const bf16* ga = A + (size_t)(row0 + trow) * K + k0 + (schunk << 3);
      __builtin_amdgcn_global_load_lds(
          (const __attribute__((address_space(1))) void*)ga,
          (__attribute__((address_space(3))) void*)((char*)&As[0][0] + (unsigned)c * 16),
          16, 0, 0);
    }
    #pragma unroll
    for (int r = 0; r < 4; ++r) {
      int c = r * 256 + tid;
      int trow = c >> 3;
      int schunk = SWZ ? ((c & 7) ^ (trow & 7)) : (c & 7);
      const bf16* gb = BT + (size_t)(col0 + trow) * K + k0 + (schunk << 3);
      __builtin_amdgcn_global_load_lds(
          (const __attribute__((address_space(1))) void*)gb,
          (__attribute__((address_space(3))) void*)((char*)&Bs[0][0] + (unsigned)c * 16),
          16, 0, 0);
    }
    __syncthreads();
    int l15 = lane & 15;
    int g8 = (lane >> 4) << 3;
    int sx = SWZ ? ((l15 & 7) << 3) : 0;
    #pragma unroll
    for (int kk = 0; kk < 64; kk += 32) {
      short8 a[MREP], b[4];
      #pragma unroll
      for (int m = 0; m < MREP; ++m)
        a[m] = *(const short8*)&As[wr * (MREP * 16) + m * 16 + l15][(kk + g8) ^ sx];
      #pragma unroll
      for (int n = 0; n < 4; ++n)
        b[n] = *(const short8*)&Bs[wc * 64 + n * 16 + l15][(kk + g8) ^ sx];
      #pragma unroll
      for (int m = 0; m < MREP; ++m)
        #pragma unroll
        for (int n = 0; n < 4; ++n)
          acc[m][n] = __builtin_amdgcn_mfma_f32_16x16x32_bf16(a[m], b[n], acc[m][n], 0, 0, 0);
    }
    __syncthreads();
  }

  int cr = lane >> 4;
  int cc = lane & 15;
  #pragma unroll
  for (int m = 0; m < MREP; ++m) {
    #pragma unroll
    for (int n = 0; n < 4; ++n) {
      int col = col0 + wc * 64 + n * 16 + cc;
      if (col >= N) continue;
      float bv = bias ? bias[col] : 0.f;
      #pragma unroll
      for (int e = 0; e < 4; ++e) {
        int row = row0 + wr * (MREP * 16) + m * 16 + cr * 4 + e;
        float v = acc[m][n][e] + bv;
        size_t off = (size_t)row * N + col;
        if (Rres) v += Rres[off];
        if (relu) v = fmaxf(v, 0.f);
        if (Cf)  Cf[off] = v;
        if (Cbf) Cbf[off] = __float2bfloat16(v);
      }
    }
  }

  if (ps) {
    #pragma unroll
    for (int m = 0; m < MREP; ++m) {
      #pragma unroll
      for (int e = 0; e < 4; ++e) {
        float ssum = 0.f;
        #pragma unroll
        for (int n = 0; n < 4; ++n) {
          int col = col0 + wc * 64 + n * 16 + cc;
          float val = (col < N) ? (acc[m][n][e] + (bias ? bias[col] : 0.f)) : -1e30f;
          ssum += __expf(val);
        }
        ssum += __shfl_xor(ssum, 1);
        ssum += __shfl_xor(ssum, 2);
        ssum += __shfl_xor(ssum, 4);
        ssum += __shfl_xor(ssum, 8);
        if (cc == 0) {
          int rl = wr * (MREP * 16) + m * 16 + cr * 4 + e;
          ps2[rl][wc] = ssum;
        }
      }
    }
    __syncthreads();
    for (int i = tid; i < MREP * 32; i += 256) {
      size_t o = (size_t)(row0 + i) * ncb + cb;
      ps[o] = ps2[i][0] + ps2[i][1];
    }
  }
}

// ---------------- LM-head GEMM: 2-phase pipeline, 32 KB LDS (5 blocks/CU) ----------------
// R10's proven schedule (STAGE(next) -> MFMA(cur) -> vmcnt(0) -> barrier), with
// ps2 OVERLAID on As[0]: the final K-tile (t=23, odd) reads only buffer 1, and all
// waves crossed the t=22 barrier, so As[0] is dead in the epilogue -> total LDS
// exactly 32768 B -> 5 blocks/CU (vs 33792 -> 4; R3-vs-R9 delta showed that one
// block is worth ~300us here).
#define LBK 32
#define LMK 768
__global__ __launch_bounds__(256) void lm_gemm(
    const bf16* __restrict__ A, const bf16* __restrict__ BT,
    float* __restrict__ Cf, const float* __restrict__ bias,
    float* __restrict__ ps, int M, int N, int ncb)
{
  __shared__ bf16 As[2][128][LBK];   // 16 KB
  __shared__ bf16 Bs[2][128][LBK];   // 16 KB   -> total 32768
  float (*ps2)[2] = reinterpret_cast<float(*)[2]>(&As[0][0][0]);  // overlay (As[0] dead at epilogue)
  int tid = threadIdx.x;
  int lane = tid & 63;
  int w = __builtin_amdgcn_readfirstlane(tid >> 6);
  int wr = w >> 1, wc = w & 1;
  int row0 = blockIdx.y * 128, col0 = blockIdx.x * 128;
  int l15 = lane & 15;
  int g8 = (lane >> 4) << 3;

  f32x4 acc[4][4] = {};
  const int nk = LMK / LBK;    // 24 (even -> final tile uses buffer 1, As[0] dead)

#define LM_STAGE(b, k0)                                                        \
  {                                                                            \
    _Pragma("unroll")                                                          \
    for (int r = 0; r < 2; ++r) {                                              \
      int c = r * 256 + tid;                                                   \
      int trow = c >> 2, tcol = (c & 3) << 3;                                  \
      const bf16* ga = A + (size_t)(row0 + trow) * LMK + (k0) + tcol;          \
      __builtin_amdgcn_global_load_lds(                                        \
          (const __attribute__((address_space(1))) void*)ga,                   \
          (__attribute__((address_space(3))) void*)((char*)&As[b][0][0] + (unsigned)c * 16), \
          16, 0, 0);                                                           \
    }                                                                          \
    _Pragma("unroll")                                                          \
    for (int r = 0; r < 2; ++r) {                                              \
      int c = r * 256 + tid;                                                   \
      int trow = c >> 2, tcol = (c & 3) << 3;                                  \
      const bf16* gb = BT + (size_t)(col0 + trow) * LMK + (k0) + tcol;         \
      __builtin_amdgcn_global_load_lds(                                        \
          (const __attribute__((address_space(1))) void*)gb,                   \
          (__attribute__((address_space(3))) void*)((char*)&Bs[b][0][0] + (unsigned)c * 16), \
          16, 0, 0);                                                           \
    }                                                                          \
  }

  LM_STAGE(0, 0);
  asm volatile("s_waitcnt vmcnt(0)" ::: "memory");
  __builtin_amdgcn_s_barrier();

  int cur = 0;
  for (int t = 0; t < nk - 1; ++t) {
    LM_STAGE(cur ^ 1, (t + 1) * LBK);
    short8 a[4], bb[4];
    #pragma unroll
    for (int m = 0; m < 4; ++m)
      a[m] = *(const short8*)&As[cur][wr * 64 + m * 16 + l15][g8];
    #pragma unroll
    for (int n = 0; n < 4; ++n)
      bb[n] = *(const short8*)&Bs[cur][wc * 64 + n * 16 + l15][g8];
    #pragma unroll
    for (int m = 0; m < 4; ++m)
      #pragma unroll
      for (int n = 0; n < 4; ++n)
        acc[m][n] = __builtin_amdgcn_mfma_f32_16x16x32_bf16(a[m], bb[n], acc[m][n], 0, 0, 0);
    asm volatile("s_waitcnt vmcnt(0)" ::: "memory");
    __builtin_amdgcn_s_barrier();
    cur ^= 1;
  }
  {
    short8 a[4], bb[4];
    #pragma unroll
    for (int m = 0; m < 4; ++m)
      a[m] = *(const short8*)&As[cur][wr * 64 + m * 16 + l15][g8];
    #pragma unroll
    for (int n = 0; n < 4; ++n)
      bb[n] = *(const short8*)&Bs[cur][wc * 64 + n * 16 + l15][g8];
    #pragma unroll
    for (int m = 0; m < 4; ++m)
      #pragma unroll
      for (int n = 0; n < 4; ++n)
        acc[m][n] = __builtin_amdgcn_mfma_f32_16x16x32_bf16(a[m], bb[n], acc[m][n], 0, 0, 0);
  }

  int cr = lane >> 4;
  int cc = lane & 15;
  #pragma unroll
  for (int m = 0; m < 4; ++m) {
    #pragma unroll
    for (int n = 0; n < 4; ++n) {
      int col = col0 + wc * 64 + n * 16 + cc;
      if (col >= N) continue;
      float bv = bias[col];
      #pragma unroll
      for (int e = 0; e < 4; ++e) {
        int row = row0 + wr * 64 + m * 16 + cr * 4 + e;
        Cf[(size_t)row * N + col] = acc[m][n][e] + bv;
      }
    }
  }

  // fused per-row sum-exp partials (M=0 shift; logits O(5), f32-safe).
  // ps2 lives in As[0] bytes — dead since the t=22 barrier (final tile reads buf 1).
  #pragma unroll
  for (int m = 0; m < 4; ++m) {
    #pragma unroll
    for (int e = 0; e < 4; ++e) {
      float ssum = 0.f;
      #pragma unroll
      for (int n = 0; n < 4; ++n) {
        int col = col0 + wc * 64 + n * 16 + cc;
        float val = (col < N) ? (acc[m][n][e] + bias[col]) : -1e30f;
        ssum += __expf(val);
      }
      ssum += __shfl_xor(ssum, 1);
      ssum += __shfl_xor(ssum, 2);
      ssum += __shfl_xor(ssum, 4);
      ssum += __shfl_xor(ssum, 8);
      if (cc == 0) ps2[wr * 64 + m * 16 + cr * 4 + e][wc] = ssum;
    }
  }
  __syncthreads();
  for (int i = tid; i < 128; i += 256) {
    size_t o = (size_t)(row0 + i) * ncb + blockIdx.x;
    ps[o] = ps2[i][0] + ps2[i][1];
  }
#undef LM_STAGE
}

// ---------------- flash attention, MFMA, online softmax ----------------
static __device__ inline unsigned short bfbits(float x) {
  bf16 h = __float2bfloat16(x);
  return *reinterpret_cast<unsigned short*>(&h);
}

__global__ __launch_bounds__(256) void fattn_kernel(
    const bf16* __restrict__ QKV, bf16* __restrict__ O)
{
  __shared__ unsigned short Ks[64][72];
  __shared__ unsigned short Vt[64][72];
  __shared__ unsigned short Pl[4][16][72];
  int qt = blockIdx.x, h = blockIdx.y, b = blockIdx.z;
  int tid = threadIdx.x;
  int lane = tid & 63;
  int w = tid >> 6;
  int l15 = lane & 15, g = lane >> 4;
  int brow = b * NT;
  int qbase = qt * 64;
  int q_loc = w * 16 + l15;

  short8 bq[2];
  {
    const bf16* qp = QKV + (size_t)(brow + qbase + q_loc) * QKVS + h * 64 + g * 8;
    bq[0] = *(const short8*)qp;
    bq[1] = *(const short8*)(qp + 32);
  }

  float m_run = -1e30f, l_run = 0.f;
  f32x4 acc[4] = {};

  for (int kt = 0; kt <= qt; ++kt) {
    int s0 = kt * 64;
    #pragma unroll
    for (int i = 0; i < 2; ++i) {
      int c = tid + i * 256;
      int row = c >> 3, colg = (c & 7) * 8;
      const bf16* kp = QKV + (size_t)(brow + s0 + row) * QKVS + NE + h * 64 + colg;
      const bf16* vp = QKV + (size_t)(brow + s0 + row) * QKVS + 2 * NE + h * 64 + colg;
      short8 kv = *(const short8*)kp;
      short8 vv = *(const short8*)vp;
      *(short8*)&Ks[row][colg] = kv;
      #pragma unroll
      for (int j = 0; j < 8; ++j)
        Vt[colg + j][row] = (unsigned short)vv[j];
    }
    __syncthreads();

    f32x4 sf[4] = {};
    #pragma unroll
    for (int kk = 0; kk < 2; ++kk) {
      #pragma unroll
      for (int m = 0; m < 4; ++m) {
        short8 a = *(const short8*)&Ks[m * 16 + l15][kk * 32 + g * 8];
        sf[m] = __builtin_amdgcn_mfma_f32_16x16x32_bf16(a, bq[kk], sf[m], 0, 0, 0);
      }
    }

    float sv[4][4];
    float mx = -1e30f;
    bool diag = (kt == qt);
    #pragma unroll
    for (int m = 0; m < 4; ++m)
      #pragma unroll
      for (int e = 0; e < 4; ++e) {
        float v = sf[m][e] * 0.125f;
        if (diag) {
          int sl = m * 16 + g * 4 + e;
          if (sl > q_loc) v = -1e30f;
        }
        sv[m][e] = v;
        mx = fmaxf(mx, v);
      }
    mx = fmaxf(mx, __shfl_xor(mx, 16));
    mx = fmaxf(mx, __shfl_xor(mx, 32));
    float m_new = fmaxf(m_run, mx);
    float p[4][4];
    float rs = 0.f;
    #pragma unroll
    for (int m = 0; m < 4; ++m)
      #pragma unroll
      for (int e = 0; e < 4; ++e) {
        float pe = __expf(sv[m][e] - m_new);
        p[m][e] = pe;
        rs += pe;
      }
    rs += __shfl_xor(rs, 16);
    rs += __shfl_xor(rs, 32);
    float sc_old = __expf(m_run - m_new);
    l_run = l_run * sc_old + rs;
    m_run = m_new;
    #pragma unroll
    for (int dm = 0; dm < 4; ++dm)
      #pragma unroll
      for (int e = 0; e < 4; ++e)
        acc[dm][e] *= sc_old;

    #pragma unroll
    for (int m = 0; m < 4; ++m)
      #pragma unroll
      for (int ep = 0; ep < 2; ++ep) {
        unsigned u = (unsigned)bfbits(p[m][2 * ep]) |
                     ((unsigned)bfbits(p[m][2 * ep + 1]) << 16);
        *(unsigned*)&Pl[w][l15][m * 16 + g * 4 + ep * 2] = u;
      }

    #pragma unroll
    for (int ks = 0; ks < 2; ++ks) {
      short8 pb = *(const short8*)&Pl[w][l15][ks * 32 + g * 8];
      #pragma unroll
      for (int dm = 0; dm < 4; ++dm) {
        short8 av = *(const short8*)&Vt[dm * 16 + l15][ks * 32 + g * 8];
        acc[dm] = __builtin_amdgcn_mfma_f32_16x16x32_bf16(av, pb, acc[dm], 0, 0, 0);
      }
    }
    __syncthreads();
  }

  float inv = 1.f / l_run;
  bf16* op = O + (size_t)(brow + qbase + q_loc) * NE + h * 64;
  #pragma unroll
  for (int dm = 0; dm < 4; ++dm)
    #pragma unroll
    for (int ep = 0; ep < 2; ++ep) {
      int d = dm * 16 + g * 4 + ep * 2;
      unsigned u = (unsigned)bfbits(acc[dm][2 * ep] * inv) |
                   ((unsigned)bfbits(acc[dm][2 * ep + 1] * inv) << 16);
      *(unsigned*)((unsigned short*)op + d) = u;
    }
}

// ---------------- NLL from fused sum-exp partials (M=0 shift) ----------------
__global__ __launch_bounds__(128) void nll_finish(
    const float* __restrict__ ps,
    const float* __restrict__ logits, const int* __restrict__ targets,
    float* __restrict__ nll)
{
  int row = blockIdx.x, tid = threadIdx.x;
  float s = 0.f;
  for (int i = tid; i < NCB_LM; i += 128)
    s += ps[(size_t)row * NCB_LM + i];
  #pragma unroll
  for (int o = 32; o > 0; o >>= 1) s += __shfl_xor(s, o);
  __shared__ float ss[2];
  if ((tid & 63) == 0) ss[tid >> 6] = s;
  __syncthreads();
  if (tid == 0) {
    float S = ss[0] + ss[1];
    float tgt = logits[(size_t)row * NV + targets[row]];
    nll[row] = logf(S) - tgt;
  }
}

__global__ __launch_bounds__(256) void loss_kernel(
    const float* __restrict__ nll, float* __restrict__ out)
{
  int tid = threadIdx.x;
  float s = 0.f;
  for (int i = tid; i < NTOK; i += 256) s += nll[i];
  #pragma unroll
  for (int o = 32; o > 0; o >>= 1) s += __shfl_xor(s, o);
  __shared__ float red[4];
  if ((tid & 63) == 0) red[tid >> 6] = s;
  __syncthreads();
  if (tid == 0) out[0] = (red[0] + red[1] + red[2] + red[3]) * (1.f / NTOK);
}

// ---------------- host ----------------
static inline void gemm(const bf16* A, const bf16* BT,
                        float* Cf, bf16* Cbf,
                        const float* bias, const float* Rres, float* ps,
                        int M, int N, int Npad, int K, int relu,
                        int mrep, hipStream_t st)
{
  int ncb = Npad / 128;
  dim3 g(ncb, M / (mrep * 32));
  if (mrep == 4)
    gemm_bf<4, true><<<g, dim3(256), 0, st>>>(A, BT, Cf, Cbf, bias, Rres, ps, M, N, K, relu, ncb);
  else
    gemm_bf<2, true><<<g, dim3(256), 0, st>>>(A, BT, Cf, Cbf, bias, Rres, ps, M, N, K, relu, ncb);
}

extern "C" void kernel_launch(void* const* d_in, const int* in_sizes, int n_in,
                              void* d_out, int out_size, void* d_ws, size_t ws_size,
                              hipStream_t stream)
{
  const int*   idx     = (const int*)  d_in[0];
  const int*   targets = (const int*)  d_in[1];
  const float* tok_emb = (const float*)d_in[2];
  const float* pos_emb = (const float*)d_in[3];
  const float* Wq      = (const float*)d_in[4];
  const float* Wk      = (const float*)d_in[5];
  const float* Wv      = (const float*)d_in[6];
  const float* Wo      = (const float*)d_in[7];
  const float* bo      = (const float*)d_in[8];
  const float* ln1_s   = (const float*)d_in[9];
  const float* ln1_b   = (const float*)d_in[10];
  const float* ln2_s   = (const float*)d_in[11];
  const float* ln2_b   = (const float*)d_in[12];
  const float* W1      = (const float*)d_in[13];
  const float* b1      = (const float*)d_in[14];
  const float* W2      = (const float*)d_in[15];
  const float* b2      = (const float*)d_in[16];
  const float* lnf_s   = (const float*)d_in[17];
  const float* lnf_b   = (const float*)d_in[18];
  const float* Wlm     = (const float*)d_in[19];
  const float* blm     = (const float*)d_in[20];
  float* out = (float*)d_out;

  const size_t XE = (size_t)NTOK * NE;
  char* p = (char*)d_ws;
  float* x     = (float*)p;         p += XE * 4;
  bf16* h_bf   = (bf16*)p;          p += XE * 2;
  bf16* qkv_bf = (bf16*)p;          p += (size_t)NTOK * QKVS * 2;
  bf16* att_bf = (bf16*)p;          p += XE * 2;
  bf16* f_bf   = (bf16*)p;          p += (size_t)NTOK * NFF * 2;
  bf16* wqkv_a = (bf16*)p;          p += (size_t)NL * QKVS * NE * 2;
  bf16* wto_a  = (bf16*)p;          p += (size_t)NL * NE * NE * 2;
  bf16* wt1_a  = (bf16*)p;          p += (size_t)NL * NFF * NE * 2;
  bf16* wt2_a  = (bf16*)p;          p += (size_t)NL * NE * NFF * 2;
  bf16* wtlm   = (bf16*)p;          p += (size_t)NVP * NE * 2;
  float* psb   = (float*)p;         p += (size_t)NTOK * NCB_LM * 4;
  float* nll   = (float*)p;         p += (size_t)NTOK * 4;

  embed_kernel<<<dim3(NTOK), dim3(256), 0, stream>>>(idx, tok_emb, pos_emb, x);

  // ---- layer weight transposes upfront, batched over layers (6 launches) ----
  tconv_kernel<<<dim3(2, 24, NL * NH), dim3(256), 0, stream>>>(
      Wq, wqkv_a, NE, NHS, NHS, NH,
      (size_t)NE * NHS, (size_t)QKVS * NE, (size_t)NHS * NE);
  tconv_kernel<<<dim3(2, 24, NL * NH), dim3(256), 0, stream>>>(
      Wk, wqkv_a + (size_t)NE * NE, NE, NHS, NHS, NH,
      (size_t)NE * NHS, (size_t)QKVS * NE, (size_t)NHS * NE);
  tconv_kernel<<<dim3(2, 24, NL * NH), dim3(256), 0, stream>>>(
      Wv, wqkv_a + (size_t)2 * NE * NE, NE, NHS, NHS, NH,
      (size_t)NE * NHS, (size_t)QKVS * NE, (size_t)NHS * NE);
  tconv_kernel<<<dim3(24, 24, NL), dim3(256), 0, stream>>>(
      Wo, wto_a, NE, NE, NE, 1, (size_t)NE * NE, (size_t)NE * NE, 0);
  tconv_kernel<<<dim3(96, 24, NL), dim3(256), 0, stream>>>(
      W1, wt1_a, NE, NFF, NFF, 1, (size_t)NE * NFF, (size_t)NFF * NE, 0);
  tconv_kernel<<<dim3(24, 96, NL), dim3(256), 0, stream>>>(
      W2, wt2_a, NFF, NE, NE, 1, (size_t)NFF * NE, (size_t)NE * NFF, 0);

  for (int l = 0; l < NL; ++l) {
    ln_kernel<<<dim3(NTOK), dim3(256), 0, stream>>>(x, ln1_s + l*NE, ln1_b + l*NE, h_bf);

    gemm(h_bf, wqkv_a + (size_t)l * QKVS * NE, nullptr, qkv_bf, nullptr, nullptr, nullptr,
         NTOK, QKVS, QKVS, NE, 0, 4, stream);

    fattn_kernel<<<dim3(NT / 64, NH, NB), dim3(256), 0, stream>>>(qkv_bf, att_bf);

    gemm(att_bf, wto_a + (size_t)l * NE * NE, x, nullptr, bo + l*NE, x, nullptr,
         NTOK, NE, NE, NE, 0, 2, stream);

    ln_kernel<<<dim3(NTOK), dim3(256), 0, stream>>>(x, ln2_s + l*NE, ln2_b + l*NE, h_bf);

    gemm(h_bf, wt1_a + (size_t)l * NFF * NE, nullptr, f_bf, b1 + l*NFF, nullptr, nullptr,
         NTOK, NFF, NFF, NE, 1, 4, stream);
    gemm(f_bf, wt2_a + (size_t)l * NE * NFF, x, nullptr, b2 + l*NE, x, nullptr,
         NTOK, NE, NE, NFF, 0, 2, stream);
  }

  ln_kernel<<<dim3(NTOK), dim3(256), 0, stream>>>(x, lnf_s, lnf_b, h_bf);

  // Wlm transpose just before the LM head (R3 ordering: leaves wtlm warm in L2/L3).
  tconv_kernel<<<dim3(NVP / 32, 24, 1), dim3(256), 0, stream>>>(
      Wlm, wtlm, NE, NV, NVP, 1, 0, 0, 0);

  // LM head: 2-phase pipeline, 32 KB LDS (ps2 overlaid), col-fastest grid.
  {
    dim3 g(NCB_LM, NTOK / 128);
    lm_gemm<<<g, dim3(256), 0, stream>>>(h_bf, wtlm, out, blm, psb,
                                         NTOK, NV, NCB_LM);
  }

  nll_finish<<<dim3(NTOK), dim3(128), 0, stream>>>(psb, out, targets, nll);
  loss_kernel<<<dim3(1), dim3(256), 0, stream>>>(nll, out + (size_t)NTOK * NV);
}

// Round 14
// 2091.110 us; speedup vs baseline: 1.2758x; 1.0114x over previous
//
#include <hip/hip_runtime.h>
#include <hip/hip_bf16.h>
#include <cstdint>
#include <cstddef>

#define NB 4
#define NT 1024
#define NE 768
#define NH 12
#define NHS 64
#define NL 6
#define NFF 3072
#define NV 50257
#define NVP 50304          // 50257 padded to /128
#define NTOK (NB*NT)       // 4096
#define NCB_LM (NVP/128)   // 393 col-blocks in LM head
#define QKVS 2304          // fused QKV row stride

typedef __attribute__((ext_vector_type(8))) short short8;
typedef __attribute__((ext_vector_type(4))) float f32x4;
typedef __hip_bfloat16 bf16;

// ---------------- embedding ----------------
__global__ __launch_bounds__(256) void embed_kernel(
    const int* __restrict__ idx, const float* __restrict__ tok,
    const float* __restrict__ pos, float* __restrict__ x)
{
  int bt = blockIdx.x;
  int token = idx[bt];
  int t = bt & (NT - 1);
  const float* tr = tok + (size_t)token * NE;
  const float* pr = pos + (size_t)t * NE;
  float* xr = x + (size_t)bt * NE;
  for (int i = threadIdx.x; i < NE; i += 256)
    xr[i] = tr[i] + pr[i];
}

// ---------------- layernorm (row = 768), bf16 out ----------------
__global__ __launch_bounds__(256) void ln_kernel(
    const float* __restrict__ in, const float* __restrict__ sc,
    const float* __restrict__ bi, bf16* __restrict__ out)
{
  int row = blockIdx.x, tid = threadIdx.x;
  const float* xr = in + (size_t)row * NE;
  float v0 = xr[tid], v1 = xr[tid + 256], v2 = xr[tid + 512];
  float s = v0 + v1 + v2;
  float ss = v0 * v0 + v1 * v1 + v2 * v2;
  #pragma unroll
  for (int o = 32; o > 0; o >>= 1) {
    s  += __shfl_xor(s, o);
    ss += __shfl_xor(ss, o);
  }
  __shared__ float r1[4], r2[4];
  if ((tid & 63) == 0) { r1[tid >> 6] = s; r2[tid >> 6] = ss; }
  __syncthreads();
  float tot = r1[0] + r1[1] + r1[2] + r1[3];
  float tss = r2[0] + r2[1] + r2[2] + r2[3];
  float mu  = tot * (1.f / NE);
  float var = tss * (1.f / NE) - mu * mu;
  float rs  = rsqrtf(var + 1e-5f);
  bf16* orow = out + (size_t)row * NE;
  orow[tid]       = __float2bfloat16((v0 - mu) * rs * sc[tid]       + bi[tid]);
  orow[tid + 256] = __float2bfloat16((v1 - mu) * rs * sc[tid + 256] + bi[tid + 256]);
  orow[tid + 512] = __float2bfloat16((v2 - mu) * rs * sc[tid + 512] + bi[tid + 512]);
}

// ------- transpose+convert: src f32 [R][Cs] -> dst bf16 [Cd][R], batched over z -------
__global__ __launch_bounds__(256) void tconv_kernel(
    const float* __restrict__ src, bf16* __restrict__ dst,
    int R, int Cs, int Cd, int zdiv,
    size_t srcZstr, size_t dstLstr, size_t dstHstr)
{
  __shared__ float t[32][33];
  int z = blockIdx.z;
  int l = z / zdiv, h = z - l * zdiv;
  src += (size_t)z * srcZstr;
  dst += (size_t)l * dstLstr + (size_t)h * dstHstr;
  int c0 = blockIdx.x * 32, r0 = blockIdx.y * 32;
  int tx = threadIdx.x & 31, ty = threadIdx.x >> 5;
  #pragma unroll
  for (int i = 0; i < 32; i += 8) {
    int r = r0 + ty + i, c = c0 + tx;
    t[ty + i][tx] = (c < Cs) ? src[(size_t)r * Cs + c] : 0.f;
  }
  __syncthreads();
  #pragma unroll
  for (int i = 0; i < 32; i += 8) {
    int c = c0 + ty + i, r = r0 + tx;
    if (c < Cd) dst[(size_t)c * R + r] = __float2bfloat16(t[tx][ty + i]);
  }
}

// ---------------- bf16 MFMA GEMM (m97 structure) — layer GEMMs (R9 proven) ----------------
template<int MREP, bool SWZ>
__global__ __launch_bounds__(256) void gemm_bf(
    const bf16* __restrict__ A,
    const bf16* __restrict__ BT,
    float* __restrict__ Cf, bf16* __restrict__ Cbf,
    const float* __restrict__ bias, const float* __restrict__ Rres,
    float* __restrict__ ps,
    int M, int N, int K, int relu, int ncb)
{
  constexpr int BMT = MREP * 32;
  __shared__ bf16 As[BMT][64];
  __shared__ bf16 Bs[128][64];
  __shared__ float ps2[BMT][2];
  int tid = threadIdx.x;
  int lane = tid & 63;
  int w = __builtin_amdgcn_readfirstlane(tid >> 6);
  int wr = w >> 1, wc = w & 1;
  int cb = blockIdx.x;
  int row0 = blockIdx.y * BMT;
  int col0 = cb * 128;

  f32x4 acc[MREP][4] = {};

  for (int k0 = 0; k0 < K; k0 += 64) {
    #pragma unroll
    for (int r = 0; r < MREP; ++r) {
      int c = r * 256 + tid;
      int trow = c >> 3;
      int schunk = SWZ ? ((c & 7) ^ (trow & 7)) : (c & 7);
      const bf16* ga = A + (size_t)(row0 + trow) * K + k0 + (schunk << 3);
      __builtin_amdgcn_global_load_lds(
          (const __attribute__((address_space(1))) void*)ga,
          (__attribute__((address_space(3))) void*)((char*)&As[0][0] + (unsigned)c * 16),
          16, 0, 0);
    }
    #pragma unroll
    for (int r = 0; r < 4; ++r) {
      int c = r * 256 + tid;
      int trow = c >> 3;
      int schunk = SWZ ? ((c & 7) ^ (trow & 7)) : (c & 7);
      const bf16* gb = BT + (size_t)(col0 + trow) * K + k0 + (schunk << 3);
      __builtin_amdgcn_global_load_lds(
          (const __attribute__((address_space(1))) void*)gb,
          (__attribute__((address_space(3))) void*)((char*)&Bs[0][0] + (unsigned)c * 16),
          16, 0, 0);
    }
    __syncthreads();
    int l15 = lane & 15;
    int g8 = (lane >> 4) << 3;
    int sx = SWZ ? ((l15 & 7) << 3) : 0;
    #pragma unroll
    for (int kk = 0; kk < 64; kk += 32) {
      short8 a[MREP], b[4];
      #pragma unroll
      for (int m = 0; m < MREP; ++m)
        a[m] = *(const short8*)&As[wr * (MREP * 16) + m * 16 + l15][(kk + g8) ^ sx];
      #pragma unroll
      for (int n = 0; n < 4; ++n)
        b[n] = *(const short8*)&Bs[wc * 64 + n * 16 + l15][(kk + g8) ^ sx];
      #pragma unroll
      for (int m = 0; m < MREP; ++m)
        #pragma unroll
        for (int n = 0; n < 4; ++n)
          acc[m][n] = __builtin_amdgcn_mfma_f32_16x16x32_bf16(a[m], b[n], acc[m][n], 0, 0, 0);
    }
    __syncthreads();
  }

  int cr = lane >> 4;
  int cc = lane & 15;
  #pragma unroll
  for (int m = 0; m < MREP; ++m) {
    #pragma unroll
    for (int n = 0; n < 4; ++n) {
      int col = col0 + wc * 64 + n * 16 + cc;
      if (col >= N) continue;
      float bv = bias ? bias[col] : 0.f;
      #pragma unroll
      for (int e = 0; e < 4; ++e) {
        int row = row0 + wr * (MREP * 16) + m * 16 + cr * 4 + e;
        float v = acc[m][n][e] + bv;
        size_t off = (size_t)row * N + col;
        if (Rres) v += Rres[off];
        if (relu) v = fmaxf(v, 0.f);
        if (Cf)  Cf[off] = v;
        if (Cbf) Cbf[off] = __float2bfloat16(v);
      }
    }
  }

  if (ps) {
    #pragma unroll
    for (int m = 0; m < MREP; ++m) {
      #pragma unroll
      for (int e = 0; e < 4; ++e) {
        float ssum = 0.f;
        #pragma unroll
        for (int n = 0; n < 4; ++n) {
          int col = col0 + wc * 64 + n * 16 + cc;
          float val = (col < N) ? (acc[m][n][e] + (bias ? bias[col] : 0.f)) : -1e30f;
          ssum += __expf(val);
        }
        ssum += __shfl_xor(ssum, 1);
        ssum += __shfl_xor(ssum, 2);
        ssum += __shfl_xor(ssum, 4);
        ssum += __shfl_xor(ssum, 8);
        if (cc == 0) {
          int rl = wr * (MREP * 16) + m * 16 + cr * 4 + e;
          ps2[rl][wc] = ssum;
        }
      }
    }
    __syncthreads();
    for (int i = tid; i < MREP * 32; i += 256) {
      size_t o = (size_t)(row0 + i) * ncb + cb;
      ps[o] = ps2[i][0] + ps2[i][1];
    }
  }
}

// ---------------- LM-head GEMM: 2-phase pipeline, 32 KB LDS (R13 proven) ----------------
#define LBK 32
#define LMK 768
__global__ __launch_bounds__(256) void lm_gemm(
    const bf16* __restrict__ A, const bf16* __restrict__ BT,
    float* __restrict__ Cf, const float* __restrict__ bias,
    float* __restrict__ ps, int M, int N, int ncb)
{
  __shared__ bf16 As[2][128][LBK];   // 16 KB
  __shared__ bf16 Bs[2][128][LBK];   // 16 KB   -> total 32768
  float (*ps2)[2] = reinterpret_cast<float(*)[2]>(&As[0][0][0]);  // overlay (As[0] dead at epilogue)
  int tid = threadIdx.x;
  int lane = tid & 63;
  int w = __builtin_amdgcn_readfirstlane(tid >> 6);
  int wr = w >> 1, wc = w & 1;
  int row0 = blockIdx.y * 128, col0 = blockIdx.x * 128;
  int l15 = lane & 15;
  int g8 = (lane >> 4) << 3;

  f32x4 acc[4][4] = {};
  const int nk = LMK / LBK;    // 24 (even -> final tile uses buffer 1, As[0] dead)

#define LM_STAGE(b, k0)                                                        \
  {                                                                            \
    _Pragma("unroll")                                                          \
    for (int r = 0; r < 2; ++r) {                                              \
      int c = r * 256 + tid;                                                   \
      int trow = c >> 2, tcol = (c & 3) << 3;                                  \
      const bf16* ga = A + (size_t)(row0 + trow) * LMK + (k0) + tcol;          \
      __builtin_amdgcn_global_load_lds(                                        \
          (const __attribute__((address_space(1))) void*)ga,                   \
          (__attribute__((address_space(3))) void*)((char*)&As[b][0][0] + (unsigned)c * 16), \
          16, 0, 0);                                                           \
    }                                                                          \
    _Pragma("unroll")                                                          \
    for (int r = 0; r < 2; ++r) {                                              \
      int c = r * 256 + tid;                                                   \
      int trow = c >> 2, tcol = (c & 3) << 3;                                  \
      const bf16* gb = BT + (size_t)(col0 + trow) * LMK + (k0) + tcol;         \
      __builtin_amdgcn_global_load_lds(                                        \
          (const __attribute__((address_space(1))) void*)gb,                   \
          (__attribute__((address_space(3))) void*)((char*)&Bs[b][0][0] + (unsigned)c * 16), \
          16, 0, 0);                                                           \
    }                                                                          \
  }

  LM_STAGE(0, 0);
  asm volatile("s_waitcnt vmcnt(0)" ::: "memory");
  __builtin_amdgcn_s_barrier();

  int cur = 0;
  for (int t = 0; t < nk - 1; ++t) {
    LM_STAGE(cur ^ 1, (t + 1) * LBK);
    short8 a[4], bb[4];
    #pragma unroll
    for (int m = 0; m < 4; ++m)
      a[m] = *(const short8*)&As[cur][wr * 64 + m * 16 + l15][g8];
    #pragma unroll
    for (int n = 0; n < 4; ++n)
      bb[n] = *(const short8*)&Bs[cur][wc * 64 + n * 16 + l15][g8];
    #pragma unroll
    for (int m = 0; m < 4; ++m)
      #pragma unroll
      for (int n = 0; n < 4; ++n)
        acc[m][n] = __builtin_amdgcn_mfma_f32_16x16x32_bf16(a[m], bb[n], acc[m][n], 0, 0, 0);
    asm volatile("s_waitcnt vmcnt(0)" ::: "memory");
    __builtin_amdgcn_s_barrier();
    cur ^= 1;
  }
  {
    short8 a[4], bb[4];
    #pragma unroll
    for (int m = 0; m < 4; ++m)
      a[m] = *(const short8*)&As[cur][wr * 64 + m * 16 + l15][g8];
    #pragma unroll
    for (int n = 0; n < 4; ++n)
      bb[n] = *(const short8*)&Bs[cur][wc * 64 + n * 16 + l15][g8];
    #pragma unroll
    for (int m = 0; m < 4; ++m)
      #pragma unroll
      for (int n = 0; n < 4; ++n)
        acc[m][n] = __builtin_amdgcn_mfma_f32_16x16x32_bf16(a[m], bb[n], acc[m][n], 0, 0, 0);
  }

  int cr = lane >> 4;
  int cc = lane & 15;
  #pragma unroll
  for (int m = 0; m < 4; ++m) {
    #pragma unroll
    for (int n = 0; n < 4; ++n) {
      int col = col0 + wc * 64 + n * 16 + cc;
      if (col >= N) continue;
      float bv = bias[col];
      #pragma unroll
      for (int e = 0; e < 4; ++e) {
        int row = row0 + wr * 64 + m * 16 + cr * 4 + e;
        Cf[(size_t)row * N + col] = acc[m][n][e] + bv;
      }
    }
  }

  #pragma unroll
  for (int m = 0; m < 4; ++m) {
    #pragma unroll
    for (int e = 0; e < 4; ++e) {
      float ssum = 0.f;
      #pragma unroll
      for (int n = 0; n < 4; ++n) {
        int col = col0 + wc * 64 + n * 16 + cc;
        float val = (col < N) ? (acc[m][n][e] + bias[col]) : -1e30f;
        ssum += __expf(val);
      }
      ssum += __shfl_xor(ssum, 1);
      ssum += __shfl_xor(ssum, 2);
      ssum += __shfl_xor(ssum, 4);
      ssum += __shfl_xor(ssum, 8);
      if (cc == 0) ps2[wr * 64 + m * 16 + cr * 4 + e][wc] = ssum;
    }
  }
  __syncthreads();
  for (int i = tid; i < 128; i += 256) {
    size_t o = (size_t)(row0 + i) * ncb + blockIdx.x;
    ps[o] = ps2[i][0] + ps2[i][1];
  }
#undef LM_STAGE
}

// ---------------- flash attention: T14 async-STAGE + T13 defer-max ----------------
static __device__ inline unsigned short bfbits(float x) {
  bf16 h = __float2bfloat16(x);
  return *reinterpret_cast<unsigned short*>(&h);
}

__global__ __launch_bounds__(256) void fattn_kernel(
    const bf16* __restrict__ QKV, bf16* __restrict__ O)
{
  __shared__ unsigned short Ks[64][72];
  __shared__ unsigned short Vt[64][72];
  __shared__ unsigned short Pl[4][16][72];
  int qt = blockIdx.x, h = blockIdx.y, b = blockIdx.z;
  int tid = threadIdx.x;
  int lane = tid & 63;
  int w = tid >> 6;
  int l15 = lane & 15, g = lane >> 4;
  int brow = b * NT;
  int qbase = qt * 64;
  int q_loc = w * 16 + l15;

  short8 bq[2];
  {
    const bf16* qp = QKV + (size_t)(brow + qbase + q_loc) * QKVS + h * 64 + g * 8;
    bq[0] = *(const short8*)qp;
    bq[1] = *(const short8*)(qp + 32);
  }

  // T14: K/V tile staged to REGISTERS first (4x short8 = 16 VGPR); loads for
  // tile kt+1 issue right after the post-write barrier so their latency hides
  // under QK^T/softmax/PV of tile kt.
  short8 kreg[2], vreg[2];
  int c0t = tid, c1t = tid + 256;
  int row0t = c0t >> 3, colg0 = (c0t & 7) * 8;
  int row1t = c1t >> 3, colg1 = (c1t & 7) * 8;

  auto LOADKV = [&](int kt) {
    int s0 = kt * 64;
    const bf16* base0 = QKV + (size_t)(brow + s0 + row0t) * QKVS + h * 64;
    const bf16* base1 = QKV + (size_t)(brow + s0 + row1t) * QKVS + h * 64;
    kreg[0] = *(const short8*)(base0 + NE + colg0);
    vreg[0] = *(const short8*)(base0 + 2 * NE + colg0);
    kreg[1] = *(const short8*)(base1 + NE + colg1);
    vreg[1] = *(const short8*)(base1 + 2 * NE + colg1);
  };

  float m_run = -1e30f, l_run = 0.f;
  f32x4 acc[4] = {};

  LOADKV(0);
  for (int kt = 0; kt <= qt; ++kt) {
    // write staged regs -> LDS (compiler waits on the loads here)
    *(short8*)&Ks[row0t][colg0] = kreg[0];
    *(short8*)&Ks[row1t][colg1] = kreg[1];
    #pragma unroll
    for (int j = 0; j < 8; ++j) {
      Vt[colg0 + j][row0t] = (unsigned short)vreg[0][j];
      Vt[colg1 + j][row1t] = (unsigned short)vreg[1][j];
    }
    __syncthreads();
    if (kt < qt) LOADKV(kt + 1);   // issue next tile's loads; overlap compute

    f32x4 sf[4] = {};
    #pragma unroll
    for (int kk = 0; kk < 2; ++kk) {
      #pragma unroll
      for (int m = 0; m < 4; ++m) {
        short8 a = *(const short8*)&Ks[m * 16 + l15][kk * 32 + g * 8];
        sf[m] = __builtin_amdgcn_mfma_f32_16x16x32_bf16(a, bq[kk], sf[m], 0, 0, 0);
      }
    }

    float sv[4][4];
    float mx = -1e30f;
    bool diag = (kt == qt);
    #pragma unroll
    for (int m = 0; m < 4; ++m)
      #pragma unroll
      for (int e = 0; e < 4; ++e) {
        float v = sf[m][e] * 0.125f;
        if (diag) {
          int sl = m * 16 + g * 4 + e;
          if (sl > q_loc) v = -1e30f;
        }
        sv[m][e] = v;
        mx = fmaxf(mx, v);
      }
    mx = fmaxf(mx, __shfl_xor(mx, 16));
    mx = fmaxf(mx, __shfl_xor(mx, 32));

    // T13 defer-max: only rescale when the new tile max exceeds m_run by >8.
    // P values then bounded by e^8 (bf16-safe, relative precision unchanged).
    if (!__all(mx - m_run <= 8.f)) {
      float m_new = fmaxf(m_run, mx);
      float sc_old = __expf(m_run - m_new);
      l_run *= sc_old;
      #pragma unroll
      for (int dm = 0; dm < 4; ++dm)
        #pragma unroll
        for (int e = 0; e < 4; ++e)
          acc[dm][e] *= sc_old;
      m_run = m_new;
    }

    float p[4][4];
    float rs = 0.f;
    #pragma unroll
    for (int m = 0; m < 4; ++m)
      #pragma unroll
      for (int e = 0; e < 4; ++e) {
        float pe = __expf(sv[m][e] - m_run);
        p[m][e] = pe;
        rs += pe;
      }
    rs += __shfl_xor(rs, 16);
    rs += __shfl_xor(rs, 32);
    l_run += rs;

    #pragma unroll
    for (int m = 0; m < 4; ++m)
      #pragma unroll
      for (int ep = 0; ep < 2; ++ep) {
        unsigned u = (unsigned)bfbits(p[m][2 * ep]) |
                     ((unsigned)bfbits(p[m][2 * ep + 1]) << 16);
        *(unsigned*)&Pl[w][l15][m * 16 + g * 4 + ep * 2] = u;
      }

    #pragma unroll
    for (int ks = 0; ks < 2; ++ks) {
      short8 pb = *(const short8*)&Pl[w][l15][ks * 32 + g * 8];
      #pragma unroll
      for (int dm = 0; dm < 4; ++dm) {
        short8 av = *(const short8*)&Vt[dm * 16 + l15][ks * 32 + g * 8];
        acc[dm] = __builtin_amdgcn_mfma_f32_16x16x32_bf16(av, pb, acc[dm], 0, 0, 0);
      }
    }
    __syncthreads();
  }

  float inv = 1.f / l_run;
  bf16* op = O + (size_t)(brow + qbase + q_loc) * NE + h * 64;
  #pragma unroll
  for (int dm = 0; dm < 4; ++dm)
    #pragma unroll
    for (int ep = 0; ep < 2; ++ep) {
      int d = dm * 16 + g * 4 + ep * 2;
      unsigned u = (unsigned)bfbits(acc[dm][2 * ep] * inv) |
                   ((unsigned)bfbits(acc[dm][2 * ep + 1] * inv) << 16);
      *(unsigned*)((unsigned short*)op + d) = u;
    }
}

// ---------------- NLL from fused sum-exp partials (M=0 shift) ----------------
__global__ __launch_bounds__(128) void nll_finish(
    const float* __restrict__ ps,
    const float* __restrict__ logits, const int* __restrict__ targets,
    float* __restrict__ nll)
{
  int row = blockIdx.x, tid = threadIdx.x;
  float s = 0.f;
  for (int i = tid; i < NCB_LM; i += 128)
    s += ps[(size_t)row * NCB_LM + i];
  #pragma unroll
  for (int o = 32; o > 0; o >>= 1) s += __shfl_xor(s, o);
  __shared__ float ss[2];
  if ((tid & 63) == 0) ss[tid >> 6] = s;
  __syncthreads();
  if (tid == 0) {
    float S = ss[0] + ss[1];
    float tgt = logits[(size_t)row * NV + targets[row]];
    nll[row] = logf(S) - tgt;
  }
}

__global__ __launch_bounds__(256) void loss_kernel(
    const float* __restrict__ nll, float* __restrict__ out)
{
  int tid = threadIdx.x;
  float s = 0.f;
  for (int i = tid; i < NTOK; i += 256) s += nll[i];
  #pragma unroll
  for (int o = 32; o > 0; o >>= 1) s += __shfl_xor(s, o);
  __shared__ float red[4];
  if ((tid & 63) == 0) red[tid >> 6] = s;
  __syncthreads();
  if (tid == 0) out[0] = (red[0] + red[1] + red[2] + red[3]) * (1.f / NTOK);
}

// ---------------- host ----------------
static inline void gemm(const bf16* A, const bf16* BT,
                        float* Cf, bf16* Cbf,
                        const float* bias, const float* Rres, float* ps,
                        int M, int N, int Npad, int K, int relu,
                        int mrep, hipStream_t st)
{
  int ncb = Npad / 128;
  dim3 g(ncb, M / (mrep * 32));
  if (mrep == 4)
    gemm_bf<4, true><<<g, dim3(256), 0, st>>>(A, BT, Cf, Cbf, bias, Rres, ps, M, N, K, relu, ncb);
  else
    gemm_bf<2, true><<<g, dim3(256), 0, st>>>(A, BT, Cf, Cbf, bias, Rres, ps, M, N, K, relu, ncb);
}

extern "C" void kernel_launch(void* const* d_in, const int* in_sizes, int n_in,
                              void* d_out, int out_size, void* d_ws, size_t ws_size,
                              hipStream_t stream)
{
  const int*   idx     = (const int*)  d_in[0];
  const int*   targets = (const int*)  d_in[1];
  const float* tok_emb = (const float*)d_in[2];
  const float* pos_emb = (const float*)d_in[3];
  const float* Wq      = (const float*)d_in[4];
  const float* Wk      = (const float*)d_in[5];
  const float* Wv      = (const float*)d_in[6];
  const float* Wo      = (const float*)d_in[7];
  const float* bo      = (const float*)d_in[8];
  const float* ln1_s   = (const float*)d_in[9];
  const float* ln1_b   = (const float*)d_in[10];
  const float* ln2_s   = (const float*)d_in[11];
  const float* ln2_b   = (const float*)d_in[12];
  const float* W1      = (const float*)d_in[13];
  const float* b1      = (const float*)d_in[14];
  const float* W2      = (const float*)d_in[15];
  const float* b2      = (const float*)d_in[16];
  const float* lnf_s   = (const float*)d_in[17];
  const float* lnf_b   = (const float*)d_in[18];
  const float* Wlm     = (const float*)d_in[19];
  const float* blm     = (const float*)d_in[20];
  float* out = (float*)d_out;

  const size_t XE = (size_t)NTOK * NE;
  char* p = (char*)d_ws;
  float* x     = (float*)p;         p += XE * 4;
  bf16* h_bf   = (bf16*)p;          p += XE * 2;
  bf16* qkv_bf = (bf16*)p;          p += (size_t)NTOK * QKVS * 2;
  bf16* att_bf = (bf16*)p;          p += XE * 2;
  bf16* f_bf   = (bf16*)p;          p += (size_t)NTOK * NFF * 2;
  bf16* wqkv_a = (bf16*)p;          p += (size_t)NL * QKVS * NE * 2;
  bf16* wto_a  = (bf16*)p;          p += (size_t)NL * NE * NE * 2;
  bf16* wt1_a  = (bf16*)p;          p += (size_t)NL * NFF * NE * 2;
  bf16* wt2_a  = (bf16*)p;          p += (size_t)NL * NE * NFF * 2;
  bf16* wtlm   = (bf16*)p;          p += (size_t)NVP * NE * 2;
  float* psb   = (float*)p;         p += (size_t)NTOK * NCB_LM * 4;
  float* nll   = (float*)p;         p += (size_t)NTOK * 4;

  embed_kernel<<<dim3(NTOK), dim3(256), 0, stream>>>(idx, tok_emb, pos_emb, x);

  tconv_kernel<<<dim3(2, 24, NL * NH), dim3(256), 0, stream>>>(
      Wq, wqkv_a, NE, NHS, NHS, NH,
      (size_t)NE * NHS, (size_t)QKVS * NE, (size_t)NHS * NE);
  tconv_kernel<<<dim3(2, 24, NL * NH), dim3(256), 0, stream>>>(
      Wk, wqkv_a + (size_t)NE * NE, NE, NHS, NHS, NH,
      (size_t)NE * NHS, (size_t)QKVS * NE, (size_t)NHS * NE);
  tconv_kernel<<<dim3(2, 24, NL * NH), dim3(256), 0, stream>>>(
      Wv, wqkv_a + (size_t)2 * NE * NE, NE, NHS, NHS, NH,
      (size_t)NE * NHS, (size_t)QKVS * NE, (size_t)NHS * NE);
  tconv_kernel<<<dim3(24, 24, NL), dim3(256), 0, stream>>>(
      Wo, wto_a, NE, NE, NE, 1, (size_t)NE * NE, (size_t)NE * NE, 0);
  tconv_kernel<<<dim3(96, 24, NL), dim3(256), 0, stream>>>(
      W1, wt1_a, NE, NFF, NFF, 1, (size_t)NE * NFF, (size_t)NFF * NE, 0);
  tconv_kernel<<<dim3(24, 96, NL), dim3(256), 0, stream>>>(
      W2, wt2_a, NFF, NE, NE, 1, (size_t)NFF * NE, (size_t)NE * NFF, 0);

  for (int l = 0; l < NL; ++l) {
    ln_kernel<<<dim3(NTOK), dim3(256), 0, stream>>>(x, ln1_s + l*NE, ln1_b + l*NE, h_bf);

    gemm(h_bf, wqkv_a + (size_t)l * QKVS * NE, nullptr, qkv_bf, nullptr, nullptr, nullptr,
         NTOK, QKVS, QKVS, NE, 0, 4, stream);

    fattn_kernel<<<dim3(NT / 64, NH, NB), dim3(256), 0, stream>>>(qkv_bf, att_bf);

    gemm(att_bf, wto_a + (size_t)l * NE * NE, x, nullptr, bo + l*NE, x, nullptr,
         NTOK, NE, NE, NE, 0, 2, stream);

    ln_kernel<<<dim3(NTOK), dim3(256), 0, stream>>>(x, ln2_s + l*NE, ln2_b + l*NE, h_bf);

    gemm(h_bf, wt1_a + (size_t)l * NFF * NE, nullptr, f_bf, b1 + l*NFF, nullptr, nullptr,
         NTOK, NFF, NFF, NE, 1, 4, stream);
    gemm(f_bf, wt2_a + (size_t)l * NE * NFF, x, nullptr, b2 + l*NE, x, nullptr,
         NTOK, NE, NE, NFF, 0, 2, stream);
  }

  ln_kernel<<<dim3(NTOK), dim3(256), 0, stream>>>(x, lnf_s, lnf_b, h_bf);

  tconv_kernel<<<dim3(NVP / 32, 24, 1), dim3(256), 0, stream>>>(
      Wlm, wtlm, NE, NV, NVP, 1, 0, 0, 0);

  {
    dim3 g(NCB_LM, NTOK / 128);
    lm_gemm<<<g, dim3(256), 0, stream>>>(h_bf, wtlm, out, blm, psb,
                                         NTOK, NV, NCB_LM);
  }

  nll_finish<<<dim3(NTOK), dim3(128), 0, stream>>>(psb, out, targets, nll);
  loss_kernel<<<dim3(1), dim3(256), 0, stream>>>(nll, out + (size_t)NTOK * NV);
}

// Round 15
// 2070.506 us; speedup vs baseline: 1.2885x; 1.0100x over previous
//
#include <hip/hip_runtime.h>
#include <hip/hip_bf16.h>
#include <cstdint>
#include <cstddef>

#define NB 4
#define NT 1024
#define NE 768
#define NH 12
#define NHS 64
#define NL 6
#define NFF 3072
#define NV 50257
#define NVP 50304          // 50257 padded to /128
#define NTOK (NB*NT)       // 4096
#define NCB_LM (NVP/128)   // 393 col-blocks in LM head
#define QKVS 2304          // fused QKV row stride

typedef __attribute__((ext_vector_type(8))) short short8;
typedef __attribute__((ext_vector_type(4))) float f32x4;
typedef __hip_bfloat16 bf16;

// ---------------- embedding ----------------
__global__ __launch_bounds__(256) void embed_kernel(
    const int* __restrict__ idx, const float* __restrict__ tok,
    const float* __restrict__ pos, float* __restrict__ x)
{
  int bt = blockIdx.x;
  int token = idx[bt];
  int t = bt & (NT - 1);
  const float* tr = tok + (size_t)token * NE;
  const float* pr = pos + (size_t)t * NE;
  float* xr = x + (size_t)bt * NE;
  for (int i = threadIdx.x; i < NE; i += 256)
    xr[i] = tr[i] + pr[i];
}

// ---------------- layernorm (row = 768), bf16 out ----------------
__global__ __launch_bounds__(256) void ln_kernel(
    const float* __restrict__ in, const float* __restrict__ sc,
    const float* __restrict__ bi, bf16* __restrict__ out)
{
  int row = blockIdx.x, tid = threadIdx.x;
  const float* xr = in + (size_t)row * NE;
  float v0 = xr[tid], v1 = xr[tid + 256], v2 = xr[tid + 512];
  float s = v0 + v1 + v2;
  float ss = v0 * v0 + v1 * v1 + v2 * v2;
  #pragma unroll
  for (int o = 32; o > 0; o >>= 1) {
    s  += __shfl_xor(s, o);
    ss += __shfl_xor(ss, o);
  }
  __shared__ float r1[4], r2[4];
  if ((tid & 63) == 0) { r1[tid >> 6] = s; r2[tid >> 6] = ss; }
  __syncthreads();
  float tot = r1[0] + r1[1] + r1[2] + r1[3];
  float tss = r2[0] + r2[1] + r2[2] + r2[3];
  float mu  = tot * (1.f / NE);
  float var = tss * (1.f / NE) - mu * mu;
  float rs  = rsqrtf(var + 1e-5f);
  bf16* orow = out + (size_t)row * NE;
  orow[tid]       = __float2bfloat16((v0 - mu) * rs * sc[tid]       + bi[tid]);
  orow[tid + 256] = __float2bfloat16((v1 - mu) * rs * sc[tid + 256] + bi[tid + 256]);
  orow[tid + 512] = __float2bfloat16((v2 - mu) * rs * sc[tid + 512] + bi[tid + 512]);
}

// ------- transpose+convert: src f32 [R][Cs] -> dst bf16 [Cd][R], batched over z -------
__global__ __launch_bounds__(256) void tconv_kernel(
    const float* __restrict__ src, bf16* __restrict__ dst,
    int R, int Cs, int Cd, int zdiv,
    size_t srcZstr, size_t dstLstr, size_t dstHstr)
{
  __shared__ float t[32][33];
  int z = blockIdx.z;
  int l = z / zdiv, h = z - l * zdiv;
  src += (size_t)z * srcZstr;
  dst += (size_t)l * dstLstr + (size_t)h * dstHstr;
  int c0 = blockIdx.x * 32, r0 = blockIdx.y * 32;
  int tx = threadIdx.x & 31, ty = threadIdx.x >> 5;
  #pragma unroll
  for (int i = 0; i < 32; i += 8) {
    int r = r0 + ty + i, c = c0 + tx;
    t[ty + i][tx] = (c < Cs) ? src[(size_t)r * Cs + c] : 0.f;
  }
  __syncthreads();
  #pragma unroll
  for (int i = 0; i < 32; i += 8) {
    int c = c0 + ty + i, r = r0 + tx;
    if (c < Cd) dst[(size_t)c * R + r] = __float2bfloat16(t[tx][ty + i]);
  }
}

// ---------------- bf16 MFMA GEMM (m97 structure) — layer GEMMs (R9 proven) ----------------
template<int MREP, bool SWZ>
__global__ __launch_bounds__(256) void gemm_bf(
    const bf16* __restrict__ A,
    const bf16* __restrict__ BT,
    float* __restrict__ Cf, bf16* __restrict__ Cbf,
    const float* __restrict__ bias, const float* __restrict__ Rres,
    float* __restrict__ ps,
    int M, int N, int K, int relu, int ncb)
{
  constexpr int BMT = MREP * 32;
  __shared__ bf16 As[BMT][64];
  __shared__ bf16 Bs[128][64];
  __shared__ float ps2[BMT][2];
  int tid = threadIdx.x;
  int lane = tid & 63;
  int w = __builtin_amdgcn_readfirstlane(tid >> 6);
  int wr = w >> 1, wc = w & 1;
  int cb = blockIdx.x;
  int row0 = blockIdx.y * BMT;
  int col0 = cb * 128;

  f32x4 acc[MREP][4] = {};

  for (int k0 = 0; k0 < K; k0 += 64) {
    #pragma unroll
    for (int r = 0; r < MREP; ++r) {
      int c = r * 256 + tid;
      int trow = c >> 3;
      int schunk = SWZ ? ((c & 7) ^ (trow & 7)) : (c & 7);
      const bf16* ga = A + (size_t)(row0 + trow) * K + k0 + (schunk << 3);
      __builtin_amdgcn_global_load_lds(
          (const __attribute__((address_space(1))) void*)ga,
          (__attribute__((address_space(3))) void*)((char*)&As[0][0] + (unsigned)c * 16),
          16, 0, 0);
    }
    #pragma unroll
    for (int r = 0; r < 4; ++r) {
      int c = r * 256 + tid;
      int trow = c >> 3;
      int schunk = SWZ ? ((c & 7) ^ (trow & 7)) : (c & 7);
      const bf16* gb = BT + (size_t)(col0 + trow) * K + k0 + (schunk << 3);
      __builtin_amdgcn_global_load_lds(
          (const __attribute__((address_space(1))) void*)gb,
          (__attribute__((address_space(3))) void*)((char*)&Bs[0][0] + (unsigned)c * 16),
          16, 0, 0);
    }
    __syncthreads();
    int l15 = lane & 15;
    int g8 = (lane >> 4) << 3;
    int sx = SWZ ? ((l15 & 7) << 3) : 0;
    #pragma unroll
    for (int kk = 0; kk < 64; kk += 32) {
      short8 a[MREP], b[4];
      #pragma unroll
      for (int m = 0; m < MREP; ++m)
        a[m] = *(const short8*)&As[wr * (MREP * 16) + m * 16 + l15][(kk + g8) ^ sx];
      #pragma unroll
      for (int n = 0; n < 4; ++n)
        b[n] = *(const short8*)&Bs[wc * 64 + n * 16 + l15][(kk + g8) ^ sx];
      #pragma unroll
      for (int m = 0; m < MREP; ++m)
        #pragma unroll
        for (int n = 0; n < 4; ++n)
          acc[m][n] = __builtin_amdgcn_mfma_f32_16x16x32_bf16(a[m], b[n], acc[m][n], 0, 0, 0);
    }
    __syncthreads();
  }

  int cr = lane >> 4;
  int cc = lane & 15;
  #pragma unroll
  for (int m = 0; m < MREP; ++m) {
    #pragma unroll
    for (int n = 0; n < 4; ++n) {
      int col = col0 + wc * 64 + n * 16 + cc;
      if (col >= N) continue;
      float bv = bias ? bias[col] : 0.f;
      #pragma unroll
      for (int e = 0; e < 4; ++e) {
        int row = row0 + wr * (MREP * 16) + m * 16 + cr * 4 + e;
        float v = acc[m][n][e] + bv;
        size_t off = (size_t)row * N + col;
        if (Rres) v += Rres[off];
        if (relu) v = fmaxf(v, 0.f);
        if (Cf)  Cf[off] = v;
        if (Cbf) Cbf[off] = __float2bfloat16(v);
      }
    }
  }

  if (ps) {
    #pragma unroll
    for (int m = 0; m < MREP; ++m) {
      #pragma unroll
      for (int e = 0; e < 4; ++e) {
        float ssum = 0.f;
        #pragma unroll
        for (int n = 0; n < 4; ++n) {
          int col = col0 + wc * 64 + n * 16 + cc;
          float val = (col < N) ? (acc[m][n][e] + (bias ? bias[col] : 0.f)) : -1e30f;
          ssum += __expf(val);
        }
        ssum += __shfl_xor(ssum, 1);
        ssum += __shfl_xor(ssum, 2);
        ssum += __shfl_xor(ssum, 4);
        ssum += __shfl_xor(ssum, 8);
        if (cc == 0) {
          int rl = wr * (MREP * 16) + m * 16 + cr * 4 + e;
          ps2[rl][wc] = ssum;
        }
      }
    }
    __syncthreads();
    for (int i = tid; i < MREP * 32; i += 256) {
      size_t o = (size_t)(row0 + i) * ncb + cb;
      ps[o] = ps2[i][0] + ps2[i][1];
    }
  }
}

// ---------------- LM-head GEMM: 2-phase pipeline, 32 KB LDS (R13 proven) ----------------
#define LBK 32
#define LMK 768
__global__ __launch_bounds__(256) void lm_gemm(
    const bf16* __restrict__ A, const bf16* __restrict__ BT,
    float* __restrict__ Cf, const float* __restrict__ bias,
    float* __restrict__ ps, int M, int N, int ncb)
{
  __shared__ bf16 As[2][128][LBK];   // 16 KB
  __shared__ bf16 Bs[2][128][LBK];   // 16 KB   -> total 32768
  float (*ps2)[2] = reinterpret_cast<float(*)[2]>(&As[0][0][0]);  // overlay (As[0] dead at epilogue)
  int tid = threadIdx.x;
  int lane = tid & 63;
  int w = __builtin_amdgcn_readfirstlane(tid >> 6);
  int wr = w >> 1, wc = w & 1;
  int row0 = blockIdx.y * 128, col0 = blockIdx.x * 128;
  int l15 = lane & 15;
  int g8 = (lane >> 4) << 3;

  f32x4 acc[4][4] = {};
  const int nk = LMK / LBK;    // 24 (even -> final tile uses buffer 1, As[0] dead)

#define LM_STAGE(b, k0)                                                        \
  {                                                                            \
    _Pragma("unroll")                                                          \
    for (int r = 0; r < 2; ++r) {                                              \
      int c = r * 256 + tid;                                                   \
      int trow = c >> 2, tcol = (c & 3) << 3;                                  \
      const bf16* ga = A + (size_t)(row0 + trow) * LMK + (k0) + tcol;          \
      __builtin_amdgcn_global_load_lds(                                        \
          (const __attribute__((address_space(1))) void*)ga,                   \
          (__attribute__((address_space(3))) void*)((char*)&As[b][0][0] + (unsigned)c * 16), \
          16, 0, 0);                                                           \
    }                                                                          \
    _Pragma("unroll")                                                          \
    for (int r = 0; r < 2; ++r) {                                              \
      int c = r * 256 + tid;                                                   \
      int trow = c >> 2, tcol = (c & 3) << 3;                                  \
      const bf16* gb = BT + (size_t)(col0 + trow) * LMK + (k0) + tcol;         \
      __builtin_amdgcn_global_load_lds(                                        \
          (const __attribute__((address_space(1))) void*)gb,                   \
          (__attribute__((address_space(3))) void*)((char*)&Bs[b][0][0] + (unsigned)c * 16), \
          16, 0, 0);                                                           \
    }                                                                          \
  }

  LM_STAGE(0, 0);
  asm volatile("s_waitcnt vmcnt(0)" ::: "memory");
  __builtin_amdgcn_s_barrier();

  int cur = 0;
  for (int t = 0; t < nk - 1; ++t) {
    LM_STAGE(cur ^ 1, (t + 1) * LBK);
    short8 a[4], bb[4];
    #pragma unroll
    for (int m = 0; m < 4; ++m)
      a[m] = *(const short8*)&As[cur][wr * 64 + m * 16 + l15][g8];
    #pragma unroll
    for (int n = 0; n < 4; ++n)
      bb[n] = *(const short8*)&Bs[cur][wc * 64 + n * 16 + l15][g8];
    #pragma unroll
    for (int m = 0; m < 4; ++m)
      #pragma unroll
      for (int n = 0; n < 4; ++n)
        acc[m][n] = __builtin_amdgcn_mfma_f32_16x16x32_bf16(a[m], bb[n], acc[m][n], 0, 0, 0);
    asm volatile("s_waitcnt vmcnt(0)" ::: "memory");
    __builtin_amdgcn_s_barrier();
    cur ^= 1;
  }
  {
    short8 a[4], bb[4];
    #pragma unroll
    for (int m = 0; m < 4; ++m)
      a[m] = *(const short8*)&As[cur][wr * 64 + m * 16 + l15][g8];
    #pragma unroll
    for (int n = 0; n < 4; ++n)
      bb[n] = *(const short8*)&Bs[cur][wc * 64 + n * 16 + l15][g8];
    #pragma unroll
    for (int m = 0; m < 4; ++m)
      #pragma unroll
      for (int n = 0; n < 4; ++n)
        acc[m][n] = __builtin_amdgcn_mfma_f32_16x16x32_bf16(a[m], bb[n], acc[m][n], 0, 0, 0);
  }

  int cr = lane >> 4;
  int cc = lane & 15;
  #pragma unroll
  for (int m = 0; m < 4; ++m) {
    #pragma unroll
    for (int n = 0; n < 4; ++n) {
      int col = col0 + wc * 64 + n * 16 + cc;
      if (col >= N) continue;
      float bv = bias[col];
      #pragma unroll
      for (int e = 0; e < 4; ++e) {
        int row = row0 + wr * 64 + m * 16 + cr * 4 + e;
        Cf[(size_t)row * N + col] = acc[m][n][e] + bv;
      }
    }
  }

  #pragma unroll
  for (int m = 0; m < 4; ++m) {
    #pragma unroll
    for (int e = 0; e < 4; ++e) {
      float ssum = 0.f;
      #pragma unroll
      for (int n = 0; n < 4; ++n) {
        int col = col0 + wc * 64 + n * 16 + cc;
        float val = (col < N) ? (acc[m][n][e] + bias[col]) : -1e30f;
        ssum += __expf(val);
      }
      ssum += __shfl_xor(ssum, 1);
      ssum += __shfl_xor(ssum, 2);
      ssum += __shfl_xor(ssum, 4);
      ssum += __shfl_xor(ssum, 8);
      if (cc == 0) ps2[wr * 64 + m * 16 + cr * 4 + e][wc] = ssum;
    }
  }
  __syncthreads();
  for (int i = tid; i < 128; i += 256) {
    size_t o = (size_t)(row0 + i) * ncb + blockIdx.x;
    ps[o] = ps2[i][0] + ps2[i][1];
  }
#undef LM_STAGE
}

// ---------------- flash attention: QBLK=128, 8 waves; T14 async-STAGE + T13 defer-max ----------------
// Tile-iterations per (b,h) drop 136 -> 72 vs QBLK=64 (staging+barriers halve,
// amortized over 2x q-rows). Tiles kt < 2*qt are causally full; kt >= 2*qt masked.
static __device__ inline unsigned short bfbits(float x) {
  bf16 h = __float2bfloat16(x);
  return *reinterpret_cast<unsigned short*>(&h);
}

__global__ __launch_bounds__(512) void fattn_kernel(
    const bf16* __restrict__ QKV, bf16* __restrict__ O)
{
  __shared__ unsigned short Ks[64][72];
  __shared__ unsigned short Vt[64][72];
  __shared__ unsigned short Pl[8][16][72];
  int qt = blockIdx.x, h = blockIdx.y, b = blockIdx.z;
  int tid = threadIdx.x;
  int lane = tid & 63;
  int w = tid >> 6;                 // 0..7
  int l15 = lane & 15, g = lane >> 4;
  int brow = b * NT;
  int qbase = qt * 128;
  int q_loc = w * 16 + l15;         // 0..127

  short8 bq[2];
  {
    const bf16* qp = QKV + (size_t)(brow + qbase + q_loc) * QKVS + h * 64 + g * 8;
    bq[0] = *(const short8*)qp;
    bq[1] = *(const short8*)(qp + 32);
  }

  // T14: one 16B chunk of K and V per thread (512 thr = 64 rows x 8 chunks)
  short8 kreg, vreg;
  int rowt = tid >> 3, colgt = (tid & 7) * 8;

  auto LOADKV = [&](int kt) {
    int s0 = kt * 64;
    const bf16* base = QKV + (size_t)(brow + s0 + rowt) * QKVS + h * 64;
    kreg = *(const short8*)(base + NE + colgt);
    vreg = *(const short8*)(base + 2 * NE + colgt);
  };

  float m_run = -1e30f, l_run = 0.f;
  f32x4 acc[4] = {};
  const int nkt = 2 * qt + 2;

  LOADKV(0);
  for (int kt = 0; kt < nkt; ++kt) {
    *(short8*)&Ks[rowt][colgt] = kreg;
    #pragma unroll
    for (int j = 0; j < 8; ++j)
      Vt[colgt + j][rowt] = (unsigned short)vreg[j];
    __syncthreads();
    if (kt + 1 < nkt) LOADKV(kt + 1);   // overlap next tile's fetch with compute

    f32x4 sf[4] = {};
    #pragma unroll
    for (int kk = 0; kk < 2; ++kk) {
      #pragma unroll
      for (int m = 0; m < 4; ++m) {
        short8 a = *(const short8*)&Ks[m * 16 + l15][kk * 32 + g * 8];
        sf[m] = __builtin_amdgcn_mfma_f32_16x16x32_bf16(a, bq[kk], sf[m], 0, 0, 0);
      }
    }

    float sv[4][4];
    float mx = -1e30f;
    bool diag = (kt >= 2 * qt);
    int sbase = kt * 64 - qbase;
    #pragma unroll
    for (int m = 0; m < 4; ++m)
      #pragma unroll
      for (int e = 0; e < 4; ++e) {
        float v = sf[m][e] * 0.125f;
        if (diag) {
          int sl = sbase + m * 16 + g * 4 + e;
          if (sl > q_loc) v = -1e30f;
        }
        sv[m][e] = v;
        mx = fmaxf(mx, v);
      }
    mx = fmaxf(mx, __shfl_xor(mx, 16));
    mx = fmaxf(mx, __shfl_xor(mx, 32));

    // T13 defer-max
    if (!__all(mx - m_run <= 8.f)) {
      float m_new = fmaxf(m_run, mx);
      float sc_old = __expf(m_run - m_new);
      l_run *= sc_old;
      #pragma unroll
      for (int dm = 0; dm < 4; ++dm)
        #pragma unroll
        for (int e = 0; e < 4; ++e)
          acc[dm][e] *= sc_old;
      m_run = m_new;
    }

    float p[4][4];
    float rs = 0.f;
    #pragma unroll
    for (int m = 0; m < 4; ++m)
      #pragma unroll
      for (int e = 0; e < 4; ++e) {
        float pe = __expf(sv[m][e] - m_run);
        p[m][e] = pe;
        rs += pe;
      }
    rs += __shfl_xor(rs, 16);
    rs += __shfl_xor(rs, 32);
    l_run += rs;

    #pragma unroll
    for (int m = 0; m < 4; ++m)
      #pragma unroll
      for (int ep = 0; ep < 2; ++ep) {
        unsigned u = (unsigned)bfbits(p[m][2 * ep]) |
                     ((unsigned)bfbits(p[m][2 * ep + 1]) << 16);
        *(unsigned*)&Pl[w][l15][m * 16 + g * 4 + ep * 2] = u;
      }

    #pragma unroll
    for (int ks = 0; ks < 2; ++ks) {
      short8 pb = *(const short8*)&Pl[w][l15][ks * 32 + g * 8];
      #pragma unroll
      for (int dm = 0; dm < 4; ++dm) {
        short8 av = *(const short8*)&Vt[dm * 16 + l15][ks * 32 + g * 8];
        acc[dm] = __builtin_amdgcn_mfma_f32_16x16x32_bf16(av, pb, acc[dm], 0, 0, 0);
      }
    }
    __syncthreads();
  }

  float inv = 1.f / l_run;
  bf16* op = O + (size_t)(brow + qbase + q_loc) * NE + h * 64;
  #pragma unroll
  for (int dm = 0; dm < 4; ++dm)
    #pragma unroll
    for (int ep = 0; ep < 2; ++ep) {
      int d = dm * 16 + g * 4 + ep * 2;
      unsigned u = (unsigned)bfbits(acc[dm][2 * ep] * inv) |
                   ((unsigned)bfbits(acc[dm][2 * ep + 1] * inv) << 16);
      *(unsigned*)((unsigned short*)op + d) = u;
    }
}

// ---------------- NLL from fused sum-exp partials (M=0 shift) ----------------
__global__ __launch_bounds__(128) void nll_finish(
    const float* __restrict__ ps,
    const float* __restrict__ logits, const int* __restrict__ targets,
    float* __restrict__ nll)
{
  int row = blockIdx.x, tid = threadIdx.x;
  float s = 0.f;
  for (int i = tid; i < NCB_LM; i += 128)
    s += ps[(size_t)row * NCB_LM + i];
  #pragma unroll
  for (int o = 32; o > 0; o >>= 1) s += __shfl_xor(s, o);
  __shared__ float ss[2];
  if ((tid & 63) == 0) ss[tid >> 6] = s;
  __syncthreads();
  if (tid == 0) {
    float S = ss[0] + ss[1];
    float tgt = logits[(size_t)row * NV + targets[row]];
    nll[row] = logf(S) - tgt;
  }
}

__global__ __launch_bounds__(256) void loss_kernel(
    const float* __restrict__ nll, float* __restrict__ out)
{
  int tid = threadIdx.x;
  float s = 0.f;
  for (int i = tid; i < NTOK; i += 256) s += nll[i];
  #pragma unroll
  for (int o = 32; o > 0; o >>= 1) s += __shfl_xor(s, o);
  __shared__ float red[4];
  if ((tid & 63) == 0) red[tid >> 6] = s;
  __syncthreads();
  if (tid == 0) out[0] = (red[0] + red[1] + red[2] + red[3]) * (1.f / NTOK);
}

// ---------------- host ----------------
static inline void gemm(const bf16* A, const bf16* BT,
                        float* Cf, bf16* Cbf,
                        const float* bias, const float* Rres, float* ps,
                        int M, int N, int Npad, int K, int relu,
                        int mrep, hipStream_t st)
{
  int ncb = Npad / 128;
  dim3 g(ncb, M / (mrep * 32));
  if (mrep == 4)
    gemm_bf<4, true><<<g, dim3(256), 0, st>>>(A, BT, Cf, Cbf, bias, Rres, ps, M, N, K, relu, ncb);
  else
    gemm_bf<2, true><<<g, dim3(256), 0, st>>>(A, BT, Cf, Cbf, bias, Rres, ps, M, N, K, relu, ncb);
}

extern "C" void kernel_launch(void* const* d_in, const int* in_sizes, int n_in,
                              void* d_out, int out_size, void* d_ws, size_t ws_size,
                              hipStream_t stream)
{
  const int*   idx     = (const int*)  d_in[0];
  const int*   targets = (const int*)  d_in[1];
  const float* tok_emb = (const float*)d_in[2];
  const float* pos_emb = (const float*)d_in[3];
  const float* Wq      = (const float*)d_in[4];
  const float* Wk      = (const float*)d_in[5];
  const float* Wv      = (const float*)d_in[6];
  const float* Wo      = (const float*)d_in[7];
  const float* bo      = (const float*)d_in[8];
  const float* ln1_s   = (const float*)d_in[9];
  const float* ln1_b   = (const float*)d_in[10];
  const float* ln2_s   = (const float*)d_in[11];
  const float* ln2_b   = (const float*)d_in[12];
  const float* W1      = (const float*)d_in[13];
  const float* b1      = (const float*)d_in[14];
  const float* W2      = (const float*)d_in[15];
  const float* b2      = (const float*)d_in[16];
  const float* lnf_s   = (const float*)d_in[17];
  const float* lnf_b   = (const float*)d_in[18];
  const float* Wlm     = (const float*)d_in[19];
  const float* blm     = (const float*)d_in[20];
  float* out = (float*)d_out;

  const size_t XE = (size_t)NTOK * NE;
  char* p = (char*)d_ws;
  float* x     = (float*)p;         p += XE * 4;
  bf16* h_bf   = (bf16*)p;          p += XE * 2;
  bf16* qkv_bf = (bf16*)p;          p += (size_t)NTOK * QKVS * 2;
  bf16* att_bf = (bf16*)p;          p += XE * 2;
  bf16* f_bf   = (bf16*)p;          p += (size_t)NTOK * NFF * 2;
  bf16* wqkv_a = (bf16*)p;          p += (size_t)NL * QKVS * NE * 2;
  bf16* wto_a  = (bf16*)p;          p += (size_t)NL * NE * NE * 2;
  bf16* wt1_a  = (bf16*)p;          p += (size_t)NL * NFF * NE * 2;
  bf16* wt2_a  = (bf16*)p;          p += (size_t)NL * NE * NFF * 2;
  bf16* wtlm   = (bf16*)p;          p += (size_t)NVP * NE * 2;
  float* psb   = (float*)p;         p += (size_t)NTOK * NCB_LM * 4;
  float* nll   = (float*)p;         p += (size_t)NTOK * 4;

  embed_kernel<<<dim3(NTOK), dim3(256), 0, stream>>>(idx, tok_emb, pos_emb, x);

  tconv_kernel<<<dim3(2, 24, NL * NH), dim3(256), 0, stream>>>(
      Wq, wqkv_a, NE, NHS, NHS, NH,
      (size_t)NE * NHS, (size_t)QKVS * NE, (size_t)NHS * NE);
  tconv_kernel<<<dim3(2, 24, NL * NH), dim3(256), 0, stream>>>(
      Wk, wqkv_a + (size_t)NE * NE, NE, NHS, NHS, NH,
      (size_t)NE * NHS, (size_t)QKVS * NE, (size_t)NHS * NE);
  tconv_kernel<<<dim3(2, 24, NL * NH), dim3(256), 0, stream>>>(
      Wv, wqkv_a + (size_t)2 * NE * NE, NE, NHS, NHS, NH,
      (size_t)NE * NHS, (size_t)QKVS * NE, (size_t)NHS * NE);
  tconv_kernel<<<dim3(24, 24, NL), dim3(256), 0, stream>>>(
      Wo, wto_a, NE, NE, NE, 1, (size_t)NE * NE, (size_t)NE * NE, 0);
  tconv_kernel<<<dim3(96, 24, NL), dim3(256), 0, stream>>>(
      W1, wt1_a, NE, NFF, NFF, 1, (size_t)NE * NFF, (size_t)NFF * NE, 0);
  tconv_kernel<<<dim3(24, 96, NL), dim3(256), 0, stream>>>(
      W2, wt2_a, NFF, NE, NE, 1, (size_t)NFF * NE, (size_t)NE * NFF, 0);

  for (int l = 0; l < NL; ++l) {
    ln_kernel<<<dim3(NTOK), dim3(256), 0, stream>>>(x, ln1_s + l*NE, ln1_b + l*NE, h_bf);

    gemm(h_bf, wqkv_a + (size_t)l * QKVS * NE, nullptr, qkv_bf, nullptr, nullptr, nullptr,
         NTOK, QKVS, QKVS, NE, 0, 4, stream);

    fattn_kernel<<<dim3(NT / 128, NH, NB), dim3(512), 0, stream>>>(qkv_bf, att_bf);

    gemm(att_bf, wto_a + (size_t)l * NE * NE, x, nullptr, bo + l*NE, x, nullptr,
         NTOK, NE, NE, NE, 0, 2, stream);

    ln_kernel<<<dim3(NTOK), dim3(256), 0, stream>>>(x, ln2_s + l*NE, ln2_b + l*NE, h_bf);

    gemm(h_bf, wt1_a + (size_t)l * NFF * NE, nullptr, f_bf, b1 + l*NFF, nullptr, nullptr,
         NTOK, NFF, NFF, NE, 1, 4, stream);
    gemm(f_bf, wt2_a + (size_t)l * NE * NFF, x, nullptr, b2 + l*NE, x, nullptr,
         NTOK, NE, NE, NFF, 0, 2, stream);
  }

  ln_kernel<<<dim3(NTOK), dim3(256), 0, stream>>>(x, lnf_s, lnf_b, h_bf);

  tconv_kernel<<<dim3(NVP / 32, 24, 1), dim3(256), 0, stream>>>(
      Wlm, wtlm, NE, NV, NVP, 1, 0, 0, 0);

  {
    dim3 g(NCB_LM, NTOK / 128);
    lm_gemm<<<g, dim3(256), 0, stream>>>(h_bf, wtlm, out, blm, psb,
                                         NTOK, NV, NCB_LM);
  }

  nll_finish<<<dim3(NTOK), dim3(128), 0, stream>>>(psb, out, targets, nll);
  loss_kernel<<<dim3(1), dim3(256), 0, stream>>>(nll, out + (size_t)NTOK * NV);
}

// Round 16
// 2024.126 us; speedup vs baseline: 1.3181x; 1.0229x over previous
//
#include <hip/hip_runtime.h>
#include <hip/hip_bf16.h>
#include <cstdint>
#include <cstddef>

#define NB 4
#define NT 1024
#define NE 768
#define NH 12
#define NHS 64
#define NL 6
#define NFF 3072
#define NV 50257
#define NVP 50304          // 50257 padded to /128
#define NTOK (NB*NT)       // 4096
#define NCB_LM (NVP/128)   // 393 col-blocks in LM head
#define QKVS 2304          // fused QKV row stride

typedef __attribute__((ext_vector_type(8))) short short8;
typedef __attribute__((ext_vector_type(4))) float f32x4;
typedef __hip_bfloat16 bf16;

// ---------------- embedding (bf16 residual out) ----------------
__global__ __launch_bounds__(256) void embed_kernel(
    const int* __restrict__ idx, const float* __restrict__ tok,
    const float* __restrict__ pos, bf16* __restrict__ x)
{
  int bt = blockIdx.x;
  int token = idx[bt];
  int t = bt & (NT - 1);
  const float* tr = tok + (size_t)token * NE;
  const float* pr = pos + (size_t)t * NE;
  bf16* xr = x + (size_t)bt * NE;
  for (int i = threadIdx.x; i < NE; i += 256)
    xr[i] = __float2bfloat16(tr[i] + pr[i]);
}

// ---------------- layernorm (row = 768), bf16 in / bf16 out ----------------
__global__ __launch_bounds__(256) void ln_kernel(
    const bf16* __restrict__ in, const float* __restrict__ sc,
    const float* __restrict__ bi, bf16* __restrict__ out)
{
  int row = blockIdx.x, tid = threadIdx.x;
  const bf16* xr = in + (size_t)row * NE;
  float v0 = __bfloat162float(xr[tid]);
  float v1 = __bfloat162float(xr[tid + 256]);
  float v2 = __bfloat162float(xr[tid + 512]);
  float s = v0 + v1 + v2;
  float ss = v0 * v0 + v1 * v1 + v2 * v2;
  #pragma unroll
  for (int o = 32; o > 0; o >>= 1) {
    s  += __shfl_xor(s, o);
    ss += __shfl_xor(ss, o);
  }
  __shared__ float r1[4], r2[4];
  if ((tid & 63) == 0) { r1[tid >> 6] = s; r2[tid >> 6] = ss; }
  __syncthreads();
  float tot = r1[0] + r1[1] + r1[2] + r1[3];
  float tss = r2[0] + r2[1] + r2[2] + r2[3];
  float mu  = tot * (1.f / NE);
  float var = tss * (1.f / NE) - mu * mu;
  float rs  = rsqrtf(var + 1e-5f);
  bf16* orow = out + (size_t)row * NE;
  orow[tid]       = __float2bfloat16((v0 - mu) * rs * sc[tid]       + bi[tid]);
  orow[tid + 256] = __float2bfloat16((v1 - mu) * rs * sc[tid + 256] + bi[tid + 256]);
  orow[tid + 512] = __float2bfloat16((v2 - mu) * rs * sc[tid + 512] + bi[tid + 512]);
}

// ------- transpose+convert: src f32 [R][Cs] -> dst bf16 [Cd][R], batched over z -------
__global__ __launch_bounds__(256) void tconv_kernel(
    const float* __restrict__ src, bf16* __restrict__ dst,
    int R, int Cs, int Cd, int zdiv,
    size_t srcZstr, size_t dstLstr, size_t dstHstr)
{
  __shared__ float t[32][33];
  int z = blockIdx.z;
  int l = z / zdiv, h = z - l * zdiv;
  src += (size_t)z * srcZstr;
  dst += (size_t)l * dstLstr + (size_t)h * dstHstr;
  int c0 = blockIdx.x * 32, r0 = blockIdx.y * 32;
  int tx = threadIdx.x & 31, ty = threadIdx.x >> 5;
  #pragma unroll
  for (int i = 0; i < 32; i += 8) {
    int r = r0 + ty + i, c = c0 + tx;
    t[ty + i][tx] = (c < Cs) ? src[(size_t)r * Cs + c] : 0.f;
  }
  __syncthreads();
  #pragma unroll
  for (int i = 0; i < 32; i += 8) {
    int c = c0 + ty + i, r = r0 + tx;
    if (c < Cd) dst[(size_t)c * R + r] = __float2bfloat16(t[tx][ty + i]);
  }
}

// ---------------- bf16 MFMA GEMM (m97 structure) — layer GEMMs (R9 proven) ----------------
// Rres is now bf16 (residual stream); residual-GEMMs write bf16 in place
// (each element is read+written by the same thread -> race-free).
template<int MREP, bool SWZ>
__global__ __launch_bounds__(256) void gemm_bf(
    const bf16* __restrict__ A,
    const bf16* __restrict__ BT,
    float* __restrict__ Cf, bf16* __restrict__ Cbf,
    const float* __restrict__ bias, const bf16* __restrict__ Rres,
    float* __restrict__ ps,
    int M, int N, int K, int relu, int ncb)
{
  constexpr int BMT = MREP * 32;
  __shared__ bf16 As[BMT][64];
  __shared__ bf16 Bs[128][64];
  __shared__ float ps2[BMT][2];
  int tid = threadIdx.x;
  int lane = tid & 63;
  int w = __builtin_amdgcn_readfirstlane(tid >> 6);
  int wr = w >> 1, wc = w & 1;
  int cb = blockIdx.x;
  int row0 = blockIdx.y * BMT;
  int col0 = cb * 128;

  f32x4 acc[MREP][4] = {};

  for (int k0 = 0; k0 < K; k0 += 64) {
    #pragma unroll
    for (int r = 0; r < MREP; ++r) {
      int c = r * 256 + tid;
      int trow = c >> 3;
      int schunk = SWZ ? ((c & 7) ^ (trow & 7)) : (c & 7);
      const bf16* ga = A + (size_t)(row0 + trow) * K + k0 + (schunk << 3);
      __builtin_amdgcn_global_load_lds(
          (const __attribute__((address_space(1))) void*)ga,
          (__attribute__((address_space(3))) void*)((char*)&As[0][0] + (unsigned)c * 16),
          16, 0, 0);
    }
    #pragma unroll
    for (int r = 0; r < 4; ++r) {
      int c = r * 256 + tid;
      int trow = c >> 3;
      int schunk = SWZ ? ((c & 7) ^ (trow & 7)) : (c & 7);
      const bf16* gb = BT + (size_t)(col0 + trow) * K + k0 + (schunk << 3);
      __builtin_amdgcn_global_load_lds(
          (const __attribute__((address_space(1))) void*)gb,
          (__attribute__((address_space(3))) void*)((char*)&Bs[0][0] + (unsigned)c * 16),
          16, 0, 0);
    }
    __syncthreads();
    int l15 = lane & 15;
    int g8 = (lane >> 4) << 3;
    int sx = SWZ ? ((l15 & 7) << 3) : 0;
    #pragma unroll
    for (int kk = 0; kk < 64; kk += 32) {
      short8 a[MREP], b[4];
      #pragma unroll
      for (int m = 0; m < MREP; ++m)
        a[m] = *(const short8*)&As[wr * (MREP * 16) + m * 16 + l15][(kk + g8) ^ sx];
      #pragma unroll
      for (int n = 0; n < 4; ++n)
        b[n] = *(const short8*)&Bs[wc * 64 + n * 16 + l15][(kk + g8) ^ sx];
      #pragma unroll
      for (int m = 0; m < MREP; ++m)
        #pragma unroll
        for (int n = 0; n < 4; ++n)
          acc[m][n] = __builtin_amdgcn_mfma_f32_16x16x32_bf16(a[m], b[n], acc[m][n], 0, 0, 0);
    }
    __syncthreads();
  }

  int cr = lane >> 4;
  int cc = lane & 15;
  #pragma unroll
  for (int m = 0; m < MREP; ++m) {
    #pragma unroll
    for (int n = 0; n < 4; ++n) {
      int col = col0 + wc * 64 + n * 16 + cc;
      if (col >= N) continue;
      float bv = bias ? bias[col] : 0.f;
      #pragma unroll
      for (int e = 0; e < 4; ++e) {
        int row = row0 + wr * (MREP * 16) + m * 16 + cr * 4 + e;
        float v = acc[m][n][e] + bv;
        size_t off = (size_t)row * N + col;
        if (Rres) v += __bfloat162float(Rres[off]);
        if (relu) v = fmaxf(v, 0.f);
        if (Cf)  Cf[off] = v;
        if (Cbf) Cbf[off] = __float2bfloat16(v);
      }
    }
  }

  if (ps) {
    #pragma unroll
    for (int m = 0; m < MREP; ++m) {
      #pragma unroll
      for (int e = 0; e < 4; ++e) {
        float ssum = 0.f;
        #pragma unroll
        for (int n = 0; n < 4; ++n) {
          int col = col0 + wc * 64 + n * 16 + cc;
          float val = (col < N) ? (acc[m][n][e] + (bias ? bias[col] : 0.f)) : -1e30f;
          ssum += __expf(val);
        }
        ssum += __shfl_xor(ssum, 1);
        ssum += __shfl_xor(ssum, 2);
        ssum += __shfl_xor(ssum, 4);
        ssum += __shfl_xor(ssum, 8);
        if (cc == 0) {
          int rl = wr * (MREP * 16) + m * 16 + cr * 4 + e;
          ps2[rl][wc] = ssum;
        }
      }
    }
    __syncthreads();
    for (int i = tid; i < MREP * 32; i += 256) {
      size_t o = (size_t)(row0 + i) * ncb + cb;
      ps[o] = ps2[i][0] + ps2[i][1];
    }
  }
}

// ---------------- LM-head GEMM: 2-phase pipeline, 32 KB LDS (R13 proven) ----------------
#define LBK 32
#define LMK 768
__global__ __launch_bounds__(256) void lm_gemm(
    const bf16* __restrict__ A, const bf16* __restrict__ BT,
    float* __restrict__ Cf, const float* __restrict__ bias,
    float* __restrict__ ps, int M, int N, int ncb)
{
  __shared__ bf16 As[2][128][LBK];   // 16 KB
  __shared__ bf16 Bs[2][128][LBK];   // 16 KB   -> total 32768
  float (*ps2)[2] = reinterpret_cast<float(*)[2]>(&As[0][0][0]);  // overlay (As[0] dead at epilogue)
  int tid = threadIdx.x;
  int lane = tid & 63;
  int w = __builtin_amdgcn_readfirstlane(tid >> 6);
  int wr = w >> 1, wc = w & 1;
  int row0 = blockIdx.y * 128, col0 = blockIdx.x * 128;
  int l15 = lane & 15;
  int g8 = (lane >> 4) << 3;

  f32x4 acc[4][4] = {};
  const int nk = LMK / LBK;    // 24 (even -> final tile uses buffer 1, As[0] dead)

#define LM_STAGE(b, k0)                                                        \
  {                                                                            \
    _Pragma("unroll")                                                          \
    for (int r = 0; r < 2; ++r) {                                              \
      int c = r * 256 + tid;                                                   \
      int trow = c >> 2, tcol = (c & 3) << 3;                                  \
      const bf16* ga = A + (size_t)(row0 + trow) * LMK + (k0) + tcol;          \
      __builtin_amdgcn_global_load_lds(                                        \
          (const __attribute__((address_space(1))) void*)ga,                   \
          (__attribute__((address_space(3))) void*)((char*)&As[b][0][0] + (unsigned)c * 16), \
          16, 0, 0);                                                           \
    }                                                                          \
    _Pragma("unroll")                                                          \
    for (int r = 0; r < 2; ++r) {                                              \
      int c = r * 256 + tid;                                                   \
      int trow = c >> 2, tcol = (c & 3) << 3;                                  \
      const bf16* gb = BT + (size_t)(col0 + trow) * LMK + (k0) + tcol;         \
      __builtin_amdgcn_global_load_lds(                                        \
          (const __attribute__((address_space(1))) void*)gb,                   \
          (__attribute__((address_space(3))) void*)((char*)&Bs[b][0][0] + (unsigned)c * 16), \
          16, 0, 0);                                                           \
    }                                                                          \
  }

  LM_STAGE(0, 0);
  asm volatile("s_waitcnt vmcnt(0)" ::: "memory");
  __builtin_amdgcn_s_barrier();

  int cur = 0;
  for (int t = 0; t < nk - 1; ++t) {
    LM_STAGE(cur ^ 1, (t + 1) * LBK);
    short8 a[4], bb[4];
    #pragma unroll
    for (int m = 0; m < 4; ++m)
      a[m] = *(const short8*)&As[cur][wr * 64 + m * 16 + l15][g8];
    #pragma unroll
    for (int n = 0; n < 4; ++n)
      bb[n] = *(const short8*)&Bs[cur][wc * 64 + n * 16 + l15][g8];
    #pragma unroll
    for (int m = 0; m < 4; ++m)
      #pragma unroll
      for (int n = 0; n < 4; ++n)
        acc[m][n] = __builtin_amdgcn_mfma_f32_16x16x32_bf16(a[m], bb[n], acc[m][n], 0, 0, 0);
    asm volatile("s_waitcnt vmcnt(0)" ::: "memory");
    __builtin_amdgcn_s_barrier();
    cur ^= 1;
  }
  {
    short8 a[4], bb[4];
    #pragma unroll
    for (int m = 0; m < 4; ++m)
      a[m] = *(const short8*)&As[cur][wr * 64 + m * 16 + l15][g8];
    #pragma unroll
    for (int n = 0; n < 4; ++n)
      bb[n] = *(const short8*)&Bs[cur][wc * 64 + n * 16 + l15][g8];
    #pragma unroll
    for (int m = 0; m < 4; ++m)
      #pragma unroll
      for (int n = 0; n < 4; ++n)
        acc[m][n] = __builtin_amdgcn_mfma_f32_16x16x32_bf16(a[m], bb[n], acc[m][n], 0, 0, 0);
  }

  int cr = lane >> 4;
  int cc = lane & 15;
  #pragma unroll
  for (int m = 0; m < 4; ++m) {
    #pragma unroll
    for (int n = 0; n < 4; ++n) {
      int col = col0 + wc * 64 + n * 16 + cc;
      if (col >= N) continue;
      float bv = bias[col];
      #pragma unroll
      for (int e = 0; e < 4; ++e) {
        int row = row0 + wr * 64 + m * 16 + cr * 4 + e;
        Cf[(size_t)row * N + col] = acc[m][n][e] + bv;
      }
    }
  }

  #pragma unroll
  for (int m = 0; m < 4; ++m) {
    #pragma unroll
    for (int e = 0; e < 4; ++e) {
      float ssum = 0.f;
      #pragma unroll
      for (int n = 0; n < 4; ++n) {
        int col = col0 + wc * 64 + n * 16 + cc;
        float val = (col < N) ? (acc[m][n][e] + bias[col]) : -1e30f;
        ssum += __expf(val);
      }
      ssum += __shfl_xor(ssum, 1);
      ssum += __shfl_xor(ssum, 2);
      ssum += __shfl_xor(ssum, 4);
      ssum += __shfl_xor(ssum, 8);
      if (cc == 0) ps2[wr * 64 + m * 16 + cr * 4 + e][wc] = ssum;
    }
  }
  __syncthreads();
  for (int i = tid; i < 128; i += 256) {
    size_t o = (size_t)(row0 + i) * ncb + blockIdx.x;
    ps[o] = ps2[i][0] + ps2[i][1];
  }
#undef LM_STAGE
}

// ---------------- flash attention: QBLK=128, 8 waves; T14 + T13 (R15 proven) ----------------
static __device__ inline unsigned short bfbits(float x) {
  bf16 h = __float2bfloat16(x);
  return *reinterpret_cast<unsigned short*>(&h);
}

__global__ __launch_bounds__(512) void fattn_kernel(
    const bf16* __restrict__ QKV, bf16* __restrict__ O)
{
  __shared__ unsigned short Ks[64][72];
  __shared__ unsigned short Vt[64][72];
  __shared__ unsigned short Pl[8][16][72];
  int qt = blockIdx.x, h = blockIdx.y, b = blockIdx.z;
  int tid = threadIdx.x;
  int lane = tid & 63;
  int w = tid >> 6;                 // 0..7
  int l15 = lane & 15, g = lane >> 4;
  int brow = b * NT;
  int qbase = qt * 128;
  int q_loc = w * 16 + l15;         // 0..127

  short8 bq[2];
  {
    const bf16* qp = QKV + (size_t)(brow + qbase + q_loc) * QKVS + h * 64 + g * 8;
    bq[0] = *(const short8*)qp;
    bq[1] = *(const short8*)(qp + 32);
  }

  short8 kreg, vreg;
  int rowt = tid >> 3, colgt = (tid & 7) * 8;

  auto LOADKV = [&](int kt) {
    int s0 = kt * 64;
    const bf16* base = QKV + (size_t)(brow + s0 + rowt) * QKVS + h * 64;
    kreg = *(const short8*)(base + NE + colgt);
    vreg = *(const short8*)(base + 2 * NE + colgt);
  };

  float m_run = -1e30f, l_run = 0.f;
  f32x4 acc[4] = {};
  const int nkt = 2 * qt + 2;

  LOADKV(0);
  for (int kt = 0; kt < nkt; ++kt) {
    *(short8*)&Ks[rowt][colgt] = kreg;
    #pragma unroll
    for (int j = 0; j < 8; ++j)
      Vt[colgt + j][rowt] = (unsigned short)vreg[j];
    __syncthreads();
    if (kt + 1 < nkt) LOADKV(kt + 1);

    f32x4 sf[4] = {};
    #pragma unroll
    for (int kk = 0; kk < 2; ++kk) {
      #pragma unroll
      for (int m = 0; m < 4; ++m) {
        short8 a = *(const short8*)&Ks[m * 16 + l15][kk * 32 + g * 8];
        sf[m] = __builtin_amdgcn_mfma_f32_16x16x32_bf16(a, bq[kk], sf[m], 0, 0, 0);
      }
    }

    float sv[4][4];
    float mx = -1e30f;
    bool diag = (kt >= 2 * qt);
    int sbase = kt * 64 - qbase;
    #pragma unroll
    for (int m = 0; m < 4; ++m)
      #pragma unroll
      for (int e = 0; e < 4; ++e) {
        float v = sf[m][e] * 0.125f;
        if (diag) {
          int sl = sbase + m * 16 + g * 4 + e;
          if (sl > q_loc) v = -1e30f;
        }
        sv[m][e] = v;
        mx = fmaxf(mx, v);
      }
    mx = fmaxf(mx, __shfl_xor(mx, 16));
    mx = fmaxf(mx, __shfl_xor(mx, 32));

    if (!__all(mx - m_run <= 8.f)) {
      float m_new = fmaxf(m_run, mx);
      float sc_old = __expf(m_run - m_new);
      l_run *= sc_old;
      #pragma unroll
      for (int dm = 0; dm < 4; ++dm)
        #pragma unroll
        for (int e = 0; e < 4; ++e)
          acc[dm][e] *= sc_old;
      m_run = m_new;
    }

    float p[4][4];
    float rs = 0.f;
    #pragma unroll
    for (int m = 0; m < 4; ++m)
      #pragma unroll
      for (int e = 0; e < 4; ++e) {
        float pe = __expf(sv[m][e] - m_run);
        p[m][e] = pe;
        rs += pe;
      }
    rs += __shfl_xor(rs, 16);
    rs += __shfl_xor(rs, 32);
    l_run += rs;

    #pragma unroll
    for (int m = 0; m < 4; ++m)
      #pragma unroll
      for (int ep = 0; ep < 2; ++ep) {
        unsigned u = (unsigned)bfbits(p[m][2 * ep]) |
                     ((unsigned)bfbits(p[m][2 * ep + 1]) << 16);
        *(unsigned*)&Pl[w][l15][m * 16 + g * 4 + ep * 2] = u;
      }

    #pragma unroll
    for (int ks = 0; ks < 2; ++ks) {
      short8 pb = *(const short8*)&Pl[w][l15][ks * 32 + g * 8];
      #pragma unroll
      for (int dm = 0; dm < 4; ++dm) {
        short8 av = *(const short8*)&Vt[dm * 16 + l15][ks * 32 + g * 8];
        acc[dm] = __builtin_amdgcn_mfma_f32_16x16x32_bf16(av, pb, acc[dm], 0, 0, 0);
      }
    }
    __syncthreads();
  }

  float inv = 1.f / l_run;
  bf16* op = O + (size_t)(brow + qbase + q_loc) * NE + h * 64;
  #pragma unroll
  for (int dm = 0; dm < 4; ++dm)
    #pragma unroll
    for (int ep = 0; ep < 2; ++ep) {
      int d = dm * 16 + g * 4 + ep * 2;
      unsigned u = (unsigned)bfbits(acc[dm][2 * ep] * inv) |
                   ((unsigned)bfbits(acc[dm][2 * ep + 1] * inv) << 16);
      *(unsigned*)((unsigned short*)op + d) = u;
    }
}

// ---------------- NLL from fused sum-exp partials (M=0 shift) ----------------
__global__ __launch_bounds__(128) void nll_finish(
    const float* __restrict__ ps,
    const float* __restrict__ logits, const int* __restrict__ targets,
    float* __restrict__ nll)
{
  int row = blockIdx.x, tid = threadIdx.x;
  float s = 0.f;
  for (int i = tid; i < NCB_LM; i += 128)
    s += ps[(size_t)row * NCB_LM + i];
  #pragma unroll
  for (int o = 32; o > 0; o >>= 1) s += __shfl_xor(s, o);
  __shared__ float ss[2];
  if ((tid & 63) == 0) ss[tid >> 6] = s;
  __syncthreads();
  if (tid == 0) {
    float S = ss[0] + ss[1];
    float tgt = logits[(size_t)row * NV + targets[row]];
    nll[row] = logf(S) - tgt;
  }
}

__global__ __launch_bounds__(256) void loss_kernel(
    const float* __restrict__ nll, float* __restrict__ out)
{
  int tid = threadIdx.x;
  float s = 0.f;
  for (int i = tid; i < NTOK; i += 256) s += nll[i];
  #pragma unroll
  for (int o = 32; o > 0; o >>= 1) s += __shfl_xor(s, o);
  __shared__ float red[4];
  if ((tid & 63) == 0) red[tid >> 6] = s;
  __syncthreads();
  if (tid == 0) out[0] = (red[0] + red[1] + red[2] + red[3]) * (1.f / NTOK);
}

// ---------------- host ----------------
static inline void gemm(const bf16* A, const bf16* BT,
                        float* Cf, bf16* Cbf,
                        const float* bias, const bf16* Rres, float* ps,
                        int M, int N, int Npad, int K, int relu,
                        int mrep, hipStream_t st)
{
  int ncb = Npad / 128;
  dim3 g(ncb, M / (mrep * 32));
  if (mrep == 4)
    gemm_bf<4, true><<<g, dim3(256), 0, st>>>(A, BT, Cf, Cbf, bias, Rres, ps, M, N, K, relu, ncb);
  else
    gemm_bf<2, true><<<g, dim3(256), 0, st>>>(A, BT, Cf, Cbf, bias, Rres, ps, M, N, K, relu, ncb);
}

extern "C" void kernel_launch(void* const* d_in, const int* in_sizes, int n_in,
                              void* d_out, int out_size, void* d_ws, size_t ws_size,
                              hipStream_t stream)
{
  const int*   idx     = (const int*)  d_in[0];
  const int*   targets = (const int*)  d_in[1];
  const float* tok_emb = (const float*)d_in[2];
  const float* pos_emb = (const float*)d_in[3];
  const float* Wq      = (const float*)d_in[4];
  const float* Wk      = (const float*)d_in[5];
  const float* Wv      = (const float*)d_in[6];
  const float* Wo      = (const float*)d_in[7];
  const float* bo      = (const float*)d_in[8];
  const float* ln1_s   = (const float*)d_in[9];
  const float* ln1_b   = (const float*)d_in[10];
  const float* ln2_s   = (const float*)d_in[11];
  const float* ln2_b   = (const float*)d_in[12];
  const float* W1      = (const float*)d_in[13];
  const float* b1      = (const float*)d_in[14];
  const float* W2      = (const float*)d_in[15];
  const float* b2      = (const float*)d_in[16];
  const float* lnf_s   = (const float*)d_in[17];
  const float* lnf_b   = (const float*)d_in[18];
  const float* Wlm     = (const float*)d_in[19];
  const float* blm     = (const float*)d_in[20];
  float* out = (float*)d_out;

  const size_t XE = (size_t)NTOK * NE;
  char* p = (char*)d_ws;
  bf16* x_bf   = (bf16*)p;          p += XE * 2;      // bf16 residual stream
  bf16* h_bf   = (bf16*)p;          p += XE * 2;
  bf16* qkv_bf = (bf16*)p;          p += (size_t)NTOK * QKVS * 2;
  bf16* att_bf = (bf16*)p;          p += XE * 2;
  bf16* f_bf   = (bf16*)p;          p += (size_t)NTOK * NFF * 2;
  bf16* wqkv_a = (bf16*)p;          p += (size_t)NL * QKVS * NE * 2;
  bf16* wto_a  = (bf16*)p;          p += (size_t)NL * NE * NE * 2;
  bf16* wt1_a  = (bf16*)p;          p += (size_t)NL * NFF * NE * 2;
  bf16* wt2_a  = (bf16*)p;          p += (size_t)NL * NE * NFF * 2;
  bf16* wtlm   = (bf16*)p;          p += (size_t)NVP * NE * 2;
  float* psb   = (float*)p;         p += (size_t)NTOK * NCB_LM * 4;
  float* nll   = (float*)p;         p += (size_t)NTOK * 4;

  embed_kernel<<<dim3(NTOK), dim3(256), 0, stream>>>(idx, tok_emb, pos_emb, x_bf);

  tconv_kernel<<<dim3(2, 24, NL * NH), dim3(256), 0, stream>>>(
      Wq, wqkv_a, NE, NHS, NHS, NH,
      (size_t)NE * NHS, (size_t)QKVS * NE, (size_t)NHS * NE);
  tconv_kernel<<<dim3(2, 24, NL * NH), dim3(256), 0, stream>>>(
      Wk, wqkv_a + (size_t)NE * NE, NE, NHS, NHS, NH,
      (size_t)NE * NHS, (size_t)QKVS * NE, (size_t)NHS * NE);
  tconv_kernel<<<dim3(2, 24, NL * NH), dim3(256), 0, stream>>>(
      Wv, wqkv_a + (size_t)2 * NE * NE, NE, NHS, NHS, NH,
      (size_t)NE * NHS, (size_t)QKVS * NE, (size_t)NHS * NE);
  tconv_kernel<<<dim3(24, 24, NL), dim3(256), 0, stream>>>(
      Wo, wto_a, NE, NE, NE, 1, (size_t)NE * NE, (size_t)NE * NE, 0);
  tconv_kernel<<<dim3(96, 24, NL), dim3(256), 0, stream>>>(
      W1, wt1_a, NE, NFF, NFF, 1, (size_t)NE * NFF, (size_t)NFF * NE, 0);
  tconv_kernel<<<dim3(24, 96, NL), dim3(256), 0, stream>>>(
      W2, wt2_a, NFF, NE, NE, 1, (size_t)NFF * NE, (size_t)NE * NFF, 0);

  for (int l = 0; l < NL; ++l) {
    ln_kernel<<<dim3(NTOK), dim3(256), 0, stream>>>(x_bf, ln1_s + l*NE, ln1_b + l*NE, h_bf);

    gemm(h_bf, wqkv_a + (size_t)l * QKVS * NE, nullptr, qkv_bf, nullptr, nullptr, nullptr,
         NTOK, QKVS, QKVS, NE, 0, 4, stream);

    fattn_kernel<<<dim3(NT / 128, NH, NB), dim3(512), 0, stream>>>(qkv_bf, att_bf);

    // x = x + att @ Wo + bo   (bf16 in-place residual)
    gemm(att_bf, wto_a + (size_t)l * NE * NE, nullptr, x_bf, bo + l*NE, x_bf, nullptr,
         NTOK, NE, NE, NE, 0, 2, stream);

    ln_kernel<<<dim3(NTOK), dim3(256), 0, stream>>>(x_bf, ln2_s + l*NE, ln2_b + l*NE, h_bf);

    gemm(h_bf, wt1_a + (size_t)l * NFF * NE, nullptr, f_bf, b1 + l*NFF, nullptr, nullptr,
         NTOK, NFF, NFF, NE, 1, 4, stream);
    // x = x + f @ W2 + b2   (bf16 in-place residual)
    gemm(f_bf, wt2_a + (size_t)l * NE * NFF, nullptr, x_bf, b2 + l*NE, x_bf, nullptr,
         NTOK, NE, NE, NFF, 0, 2, stream);
  }

  ln_kernel<<<dim3(NTOK), dim3(256), 0, stream>>>(x_bf, lnf_s, lnf_b, h_bf);

  tconv_kernel<<<dim3(NVP / 32, 24, 1), dim3(256), 0, stream>>>(
      Wlm, wtlm, NE, NV, NVP, 1, 0, 0, 0);

  {
    dim3 g(NCB_LM, NTOK / 128);
    lm_gemm<<<g, dim3(256), 0, stream>>>(h_bf, wtlm, out, blm, psb,
                                         NTOK, NV, NCB_LM);
  }

  nll_finish<<<dim3(NTOK), dim3(128), 0, stream>>>(psb, out, targets, nll);
  loss_kernel<<<dim3(1), dim3(256), 0, stream>>>(nll, out + (size_t)NTOK * NV);
}